// Round 1
// baseline (1806.227 us; speedup 1.0000x reference)
//
#include <hip/hip_runtime.h>
#include <math.h>

#define H 64
#define F 16
#define NUM_G 128

__device__ __forceinline__ int lower_bound_i(const int* a, int n, int key) {
    int lo = 0, hi = n;
    while (lo < hi) { int mid = (lo + hi) >> 1; if (a[mid] < key) lo = mid + 1; else hi = mid; }
    return lo;
}

// One 64-lane group per edge (lane = output feature h). k,q,v computed on the
// fly from the 16-wide x rows; weight columns cached in registers.
__global__ __launch_bounds__(256) void edge_kernel(
    const float* __restrict__ x_src, const float* __restrict__ x_dst,
    const int* __restrict__ src, const int* __restrict__ dst,
    const float* __restrict__ ea,
    const float* __restrict__ Wk, const float* __restrict__ bk,
    const float* __restrict__ Wq, const float* __restrict__ bq,
    const float* __restrict__ Wv, const float* __restrict__ bv,
    const float* __restrict__ We, const float* __restrict__ be,
    float* __restrict__ agg, int E)
{
    const int h = threadIdx.x & 63;
    float wk[F], wq[F], wv[F];
#pragma unroll
    for (int f = 0; f < F; ++f) {
        wk[f] = Wk[f * H + h];
        wq[f] = Wq[f * H + h];
        wv[f] = Wv[f * H + h];
    }
    const float bkh = bk[h], bqh = bq[h], bvh = bv[h];
    const float weh = We[h], beh = be[h];
    const int egrp = (blockIdx.x * (blockDim.x >> 6)) + (threadIdx.x >> 6);
    const int estep = gridDim.x * (blockDim.x >> 6);
    for (int e = egrp; e < E; e += estep) {
        const int s = src[e];
        const int d = dst[e];
        const float eav = ea[e];
        const float4* xs = (const float4*)(x_src + (size_t)s * F);
        const float4* xd = (const float4*)(x_dst + (size_t)d * F);
        float q = bqh, v = bvh, k = bkh;
#pragma unroll
        for (int f4 = 0; f4 < F / 4; ++f4) {
            float4 a = xs[f4];
            float4 b = xd[f4];
            q = fmaf(a.x, wq[4*f4+0], q); q = fmaf(a.y, wq[4*f4+1], q);
            q = fmaf(a.z, wq[4*f4+2], q); q = fmaf(a.w, wq[4*f4+3], q);
            v = fmaf(a.x, wv[4*f4+0], v); v = fmaf(a.y, wv[4*f4+1], v);
            v = fmaf(a.z, wv[4*f4+2], v); v = fmaf(a.w, wv[4*f4+3], v);
            k = fmaf(b.x, wk[4*f4+0], k); k = fmaf(b.y, wk[4*f4+1], k);
            k = fmaf(b.z, wk[4*f4+2], k); k = fmaf(b.w, wk[4*f4+3], k);
        }
        const float eh = fmaf(eav, weh, beh);
        const float gate = k + q + 2.0f * eh;
        const float sig = 1.0f / (1.0f + __expf(-gate));
        const float msg = sig * (v + eh);
        atomicAdd(&agg[(size_t)d * H + h], msg);
    }
}

// h = relu(agg + x @ Wskip + bconv); accumulate per-graph sums in registers,
// flush on (sorted) batch-id change.
__global__ __launch_bounds__(256) void finalize_kernel(
    const float* __restrict__ agg, const float* __restrict__ x,
    const float* __restrict__ Wskip, const float* __restrict__ bconv,
    const int* __restrict__ batch, float* __restrict__ pool_sum, int N)
{
    const int lane = threadIdx.x & 63;
    const int wave = (int)((blockIdx.x * blockDim.x + threadIdx.x) >> 6);
    float wsk[F];
#pragma unroll
    for (int f = 0; f < F; ++f) wsk[f] = Wskip[f * H + lane];
    const float bc = bconv[lane];
    const int n0 = wave * 64;
    float gsum = 0.f;
    int cur = -1;
    for (int i = 0; i < 64; ++i) {
        int n = n0 + i;
        if (n >= N) break;
        int g = batch[n];
        if (g != cur) {
            if (cur >= 0) atomicAdd(&pool_sum[cur * H + lane], gsum);
            gsum = 0.f; cur = g;
        }
        float acc = bc + agg[(size_t)n * H + lane];
        const float4* xr = (const float4*)(x + (size_t)n * F);
#pragma unroll
        for (int f4 = 0; f4 < F / 4; ++f4) {
            float4 a = xr[f4];
            acc = fmaf(a.x, wsk[4*f4+0], acc); acc = fmaf(a.y, wsk[4*f4+1], acc);
            acc = fmaf(a.z, wsk[4*f4+2], acc); acc = fmaf(a.w, wsk[4*f4+3], acc);
        }
        gsum += fmaxf(acc, 0.f);
    }
    if (cur >= 0) atomicAdd(&pool_sum[cur * H + lane], gsum);
}

// Per-graph node counts via binary search on the sorted batch arrays.
__global__ void count_kernel(const int* __restrict__ batch_c, int Nc,
                             const int* __restrict__ batch_b, int Nb,
                             float* __restrict__ cnt_c, float* __restrict__ cnt_b)
{
    int t = threadIdx.x;
    if (t < NUM_G) {
        int lo = lower_bound_i(batch_c, Nc, t);
        int hi = lower_bound_i(batch_c, Nc, t + 1);
        cnt_c[t] = (float)(hi - lo);
    } else if (t < 2 * NUM_G) {
        int g = t - NUM_G;
        int lo = lower_bound_i(batch_b, Nb, g);
        int hi = lower_bound_i(batch_b, Nb, g + 1);
        cnt_b[g] = (float)(hi - lo);
    }
}

// One block (64 threads) per graph: pooled[128] -> 64 -> 64 -> 64 -> 1
__global__ __launch_bounds__(64) void mlp_kernel(
    const float* __restrict__ sum_c, const float* __restrict__ sum_b,
    const float* __restrict__ cnt_c, const float* __restrict__ cnt_b,
    const float* __restrict__ W1, const float* __restrict__ b1,
    const float* __restrict__ W2, const float* __restrict__ b2,
    const float* __restrict__ W3, const float* __restrict__ b3,
    const float* __restrict__ Wout, const float* __restrict__ bout,
    float* __restrict__ out)
{
    const int g = blockIdx.x;
    const int h = threadIdx.x;
    __shared__ float pld[2 * H];
    __shared__ float hbuf[H];
    const float cc = fmaxf(cnt_c[g], 1.f);
    const float cb = fmaxf(cnt_b[g], 1.f);
    pld[h] = sum_c[g * H + h] / cc;
    pld[H + h] = sum_b[g * H + h] / cb;
    __syncthreads();
    float a1 = b1[h];
    for (int j = 0; j < 2 * H; ++j) a1 = fmaf(pld[j], W1[j * H + h], a1);
    a1 = fmaxf(a1, 0.f);
    __syncthreads();
    hbuf[h] = a1;
    __syncthreads();
    float a2 = b2[h];
    for (int j = 0; j < H; ++j) a2 = fmaf(hbuf[j], W2[j * H + h], a2);
    a2 = fmaxf(a2, 0.f);
    __syncthreads();
    hbuf[h] = a2;
    __syncthreads();
    float a3 = b3[h];
    for (int j = 0; j < H; ++j) a3 = fmaf(hbuf[j], W3[j * H + h], a3);
    a3 = fmaxf(a3, 0.f);
    float p = a3 * Wout[h];
#pragma unroll
    for (int off = 32; off > 0; off >>= 1) p += __shfl_down(p, off, 64);
    if (h == 0) out[g] = p + bout[0];
}

extern "C" void kernel_launch(void* const* d_in, const int* in_sizes, int n_in,
                              void* d_out, int out_size, void* d_ws, size_t ws_size,
                              hipStream_t stream) {
    const float* x_x   = (const float*)d_in[0];
    const float* x_c   = (const float*)d_in[1];
    const float* x_b   = (const float*)d_in[2];
    const float* ea_ac = (const float*)d_in[3];
    const float* ea_cb = (const float*)d_in[4];

    const float* Wk_ac = (const float*)d_in[5];
    const float* Wq_ac = (const float*)d_in[6];
    const float* Wv_ac = (const float*)d_in[7];
    const float* Wskip_ac = (const float*)d_in[8];
    const float* We_ac = (const float*)d_in[9];
    const float* bk_ac = (const float*)d_in[10];
    const float* bq_ac = (const float*)d_in[11];
    const float* bv_ac = (const float*)d_in[12];
    const float* be_ac = (const float*)d_in[13];
    const float* bconv_ac = (const float*)d_in[14];

    const float* Wk_cb = (const float*)d_in[15];
    const float* Wq_cb = (const float*)d_in[16];
    const float* Wv_cb = (const float*)d_in[17];
    const float* Wskip_cb = (const float*)d_in[18];
    const float* We_cb = (const float*)d_in[19];
    const float* bk_cb = (const float*)d_in[20];
    const float* bq_cb = (const float*)d_in[21];
    const float* bv_cb = (const float*)d_in[22];
    const float* be_cb = (const float*)d_in[23];
    const float* bconv_cb = (const float*)d_in[24];

    const float* W1 = (const float*)d_in[25];
    const float* b1 = (const float*)d_in[26];
    const float* W2 = (const float*)d_in[27];
    const float* b2 = (const float*)d_in[28];
    const float* W3 = (const float*)d_in[29];
    const float* b3 = (const float*)d_in[30];
    const float* Wout = (const float*)d_in[31];
    const float* bout = (const float*)d_in[32];

    const int* src_ac = (const int*)d_in[33];
    const int* dst_ac = (const int*)d_in[34];
    const int* src_cb = (const int*)d_in[35];
    const int* dst_cb = (const int*)d_in[36];
    const int* batch_c = (const int*)d_in[37];
    const int* batch_b = (const int*)d_in[38];

    const int Nx = in_sizes[0] / F;
    const int Nc = in_sizes[1] / F;
    const int Nb = in_sizes[2] / F;
    const int E1 = in_sizes[33];
    const int E2 = in_sizes[35];
    (void)Nx; (void)n_in; (void)out_size; (void)ws_size;

    // workspace layout (floats): [agg: max(Nc,Nb)*64][sum_c: 8192][sum_b: 8192][cnt_c:128][cnt_b:128]
    float* ws = (float*)d_ws;
    const size_t aggMax = (size_t)(Nc > Nb ? Nc : Nb) * H;
    float* agg   = ws;
    float* sum_c = ws + aggMax;
    float* sum_b = sum_c + NUM_G * H;
    float* cnt_c = sum_b + NUM_G * H;
    float* cnt_b = cnt_c + NUM_G;

    hipMemsetAsync(sum_c, 0, 2 * NUM_G * H * sizeof(float), stream);

    const int EDGE_BLOCKS = 2048;

    // relation ('x','a','c') -> updates 'c'
    hipMemsetAsync(agg, 0, (size_t)Nc * H * sizeof(float), stream);
    edge_kernel<<<EDGE_BLOCKS, 256, 0, stream>>>(
        x_x, x_c, src_ac, dst_ac, ea_ac,
        Wk_ac, bk_ac, Wq_ac, bq_ac, Wv_ac, bv_ac, We_ac, be_ac, agg, E1);
    finalize_kernel<<<(Nc + 255) / 256, 256, 0, stream>>>(
        agg, x_c, Wskip_ac, bconv_ac, batch_c, sum_c, Nc);

    // relation ('c','b','b') -> updates 'b'
    hipMemsetAsync(agg, 0, (size_t)Nb * H * sizeof(float), stream);
    edge_kernel<<<EDGE_BLOCKS, 256, 0, stream>>>(
        x_c, x_b, src_cb, dst_cb, ea_cb,
        Wk_cb, bk_cb, Wq_cb, bq_cb, Wv_cb, bv_cb, We_cb, be_cb, agg, E2);
    finalize_kernel<<<(Nb + 255) / 256, 256, 0, stream>>>(
        agg, x_b, Wskip_cb, bconv_cb, batch_b, sum_b, Nb);

    count_kernel<<<1, 256, 0, stream>>>(batch_c, Nc, batch_b, Nb, cnt_c, cnt_b);

    mlp_kernel<<<NUM_G, H, 0, stream>>>(
        sum_c, sum_b, cnt_c, cnt_b,
        W1, b1, W2, b2, W3, b3, Wout, bout, (float*)d_out);
}

// Round 2
// 1206.562 us; speedup vs baseline: 1.4970x; 1.4970x over previous
//
#include <hip/hip_runtime.h>
#include <math.h>

#define H 64
#define F 16
#define NUM_G 128

__device__ __forceinline__ int lower_bound_i(const int* a, int n, int key) {
    int lo = 0, hi = n;
    while (lo < hi) { int mid = (lo + hi) >> 1; if (a[mid] < key) lo = mid + 1; else hi = mid; }
    return lo;
}

// ---------------- CSR build: histogram + scan + scatter ----------------

__global__ __launch_bounds__(256) void hist_kernel(const int* __restrict__ dst,
                                                   int* __restrict__ cnt, int E) {
    int i = blockIdx.x * blockDim.x + threadIdx.x;
    if (i < E) atomicAdd(&cnt[dst[i]], 1);
}

// block b sums cnt[b*1024 .. b*1024+1023] -> bsums[b]
__global__ __launch_bounds__(256) void scan_partial(const int* __restrict__ cnt,
                                                    int* __restrict__ bsums, int n) {
    __shared__ int red[256];
    const int b = blockIdx.x, t = threadIdx.x;
    const int base = b * 1024 + t * 4;
    int s = 0;
#pragma unroll
    for (int i = 0; i < 4; ++i) { int idx = base + i; if (idx < n) s += cnt[idx]; }
    red[t] = s;
    __syncthreads();
    for (int off = 128; off > 0; off >>= 1) {
        if (t < off) red[t] += red[t + off];
        __syncthreads();
    }
    if (t == 0) bsums[b] = red[0];
}

// exclusive scan of bsums (nb <= 256), single block of 256
__global__ __launch_bounds__(256) void scan_bsums(int* __restrict__ bsums, int nb) {
    __shared__ int sh[256];
    const int t = threadIdx.x;
    sh[t] = (t < nb) ? bsums[t] : 0;
    __syncthreads();
    for (int off = 1; off < 256; off <<= 1) {
        int v = sh[t];
        int add = (t >= off) ? sh[t - off] : 0;
        __syncthreads();
        sh[t] = v + add;
        __syncthreads();
    }
    if (t < nb) bsums[t] = (t == 0) ? 0 : sh[t - 1];
}

// offsets[i] = exclusive prefix; offsets[n] = total
__global__ __launch_bounds__(256) void scan_final(const int* __restrict__ cnt,
                                                  const int* __restrict__ bsums,
                                                  int* __restrict__ offsets, int n) {
    __shared__ int red[256];
    const int b = blockIdx.x, t = threadIdx.x;
    const int base = b * 1024 + t * 4;
    int v[4]; int s = 0;
#pragma unroll
    for (int i = 0; i < 4; ++i) { int idx = base + i; v[i] = (idx < n) ? cnt[idx] : 0; s += v[i]; }
    red[t] = s;
    __syncthreads();
    for (int off = 1; off < 256; off <<= 1) {
        int val = red[t];
        int add = (t >= off) ? red[t - off] : 0;
        __syncthreads();
        red[t] = val + add;
        __syncthreads();
    }
    const int ex = (t == 0) ? 0 : red[t - 1];
    int run = bsums[b] + ex;
#pragma unroll
    for (int i = 0; i < 4; ++i) {
        int idx = base + i;
        if (idx < n) offsets[idx] = run;
        run += v[i];
    }
    if (t == 255 && b == gridDim.x - 1) offsets[n] = run;
}

__global__ __launch_bounds__(256) void scatter_kernel(const int* __restrict__ src,
                                                      const int* __restrict__ dst,
                                                      const float* __restrict__ ea,
                                                      const int* __restrict__ offsets,
                                                      int* __restrict__ cursor,
                                                      int* __restrict__ ssrc,
                                                      float* __restrict__ sea, int E) {
    int i = blockIdx.x * blockDim.x + threadIdx.x;
    if (i < E) {
        int d = dst[i];
        int p = offsets[d] + atomicAdd(&cursor[d], 1);
        ssrc[p] = src[i];
        sea[p] = ea[i];
    }
}

// ---------------- per-dst gather-reduce (no f32 scatter atomics) ----------------
// One 64-lane wave per dst node; lane = output feature h.
// h_val = relu(sum_edges sigmoid(k+q+2e)*(v+e) + x_dst@Wskip + bconv)
// then one atomicAdd into the 32KB pool_sum (L2-resident).
__global__ __launch_bounds__(256) void aggregate_kernel(
    const float* __restrict__ x_src, const float* __restrict__ x_dst,
    const int* __restrict__ offsets, const int* __restrict__ ssrc,
    const float* __restrict__ sea,
    const float* __restrict__ Wk, const float* __restrict__ bk,
    const float* __restrict__ Wq, const float* __restrict__ bq,
    const float* __restrict__ Wv, const float* __restrict__ bv,
    const float* __restrict__ We, const float* __restrict__ be,
    const float* __restrict__ Wskip, const float* __restrict__ bconv,
    const int* __restrict__ batch, float* __restrict__ pool_sum, int Ndst)
{
    const int lane = threadIdx.x & 63;
    float wq[F], wv[F], wk[F], wsk[F];
#pragma unroll
    for (int f = 0; f < F; ++f) {
        wq[f] = Wq[f * H + lane];
        wv[f] = Wv[f * H + lane];
        wk[f] = Wk[f * H + lane];
        wsk[f] = Wskip[f * H + lane];
    }
    const float bqh = bq[lane], bvh = bv[lane], bkh = bk[lane], bch = bconv[lane];
    const float weh = We[lane], beh = be[lane];
    const int wave = (blockIdx.x * (blockDim.x >> 6)) + (threadIdx.x >> 6);
    const int nw = gridDim.x * (blockDim.x >> 6);
    for (int d = wave; d < Ndst; d += nw) {
        const float4* xd = (const float4*)(x_dst + (size_t)d * F);
        float k = bkh, sk = bch;
#pragma unroll
        for (int f4 = 0; f4 < F / 4; ++f4) {
            float4 b = xd[f4];
            k = fmaf(b.x, wk[4*f4+0], k); k = fmaf(b.y, wk[4*f4+1], k);
            k = fmaf(b.z, wk[4*f4+2], k); k = fmaf(b.w, wk[4*f4+3], k);
            sk = fmaf(b.x, wsk[4*f4+0], sk); sk = fmaf(b.y, wsk[4*f4+1], sk);
            sk = fmaf(b.z, wsk[4*f4+2], sk); sk = fmaf(b.w, wsk[4*f4+3], sk);
        }
        float acc = 0.f;
        const int p0 = offsets[d];
        const int p1 = offsets[d + 1];
        int p = p0;
        if (p < p1) {
            int s = ssrc[p];
            float eav = sea[p];
            while (p < p1) {
                const float4* xs = (const float4*)(x_src + (size_t)s * F);
                float4 a0 = xs[0], a1 = xs[1], a2 = xs[2], a3 = xs[3];
                ++p;
                int sn = 0; float ean = 0.f;
                if (p < p1) { sn = ssrc[p]; ean = sea[p]; }  // prefetch next edge
                float q = bqh, v = bvh;
                q = fmaf(a0.x, wq[0], q);  q = fmaf(a0.y, wq[1], q);
                q = fmaf(a0.z, wq[2], q);  q = fmaf(a0.w, wq[3], q);
                q = fmaf(a1.x, wq[4], q);  q = fmaf(a1.y, wq[5], q);
                q = fmaf(a1.z, wq[6], q);  q = fmaf(a1.w, wq[7], q);
                q = fmaf(a2.x, wq[8], q);  q = fmaf(a2.y, wq[9], q);
                q = fmaf(a2.z, wq[10], q); q = fmaf(a2.w, wq[11], q);
                q = fmaf(a3.x, wq[12], q); q = fmaf(a3.y, wq[13], q);
                q = fmaf(a3.z, wq[14], q); q = fmaf(a3.w, wq[15], q);
                v = fmaf(a0.x, wv[0], v);  v = fmaf(a0.y, wv[1], v);
                v = fmaf(a0.z, wv[2], v);  v = fmaf(a0.w, wv[3], v);
                v = fmaf(a1.x, wv[4], v);  v = fmaf(a1.y, wv[5], v);
                v = fmaf(a1.z, wv[6], v);  v = fmaf(a1.w, wv[7], v);
                v = fmaf(a2.x, wv[8], v);  v = fmaf(a2.y, wv[9], v);
                v = fmaf(a2.z, wv[10], v); v = fmaf(a2.w, wv[11], v);
                v = fmaf(a3.x, wv[12], v); v = fmaf(a3.y, wv[13], v);
                v = fmaf(a3.z, wv[14], v); v = fmaf(a3.w, wv[15], v);
                const float eh = fmaf(eav, weh, beh);
                const float g = k + q + 2.0f * eh;
                const float sg = 1.0f / (1.0f + __expf(-g));
                acc = fmaf(sg, v + eh, acc);
                s = sn; eav = ean;
            }
        }
        const float hval = fmaxf(acc + sk, 0.f);
        atomicAdd(&pool_sum[(size_t)batch[d] * H + lane], hval);
    }
}

// Per-graph node counts via binary search on the sorted batch arrays.
__global__ void count_kernel(const int* __restrict__ batch_c, int Nc,
                             const int* __restrict__ batch_b, int Nb,
                             float* __restrict__ cnt_c, float* __restrict__ cnt_b)
{
    int t = threadIdx.x;
    if (t < NUM_G) {
        int lo = lower_bound_i(batch_c, Nc, t);
        int hi = lower_bound_i(batch_c, Nc, t + 1);
        cnt_c[t] = (float)(hi - lo);
    } else if (t < 2 * NUM_G) {
        int g = t - NUM_G;
        int lo = lower_bound_i(batch_b, Nb, g);
        int hi = lower_bound_i(batch_b, Nb, g + 1);
        cnt_b[g] = (float)(hi - lo);
    }
}

// One block (64 threads) per graph: pooled[128] -> 64 -> 64 -> 64 -> 1
__global__ __launch_bounds__(64) void mlp_kernel(
    const float* __restrict__ sum_c, const float* __restrict__ sum_b,
    const float* __restrict__ cnt_c, const float* __restrict__ cnt_b,
    const float* __restrict__ W1, const float* __restrict__ b1,
    const float* __restrict__ W2, const float* __restrict__ b2,
    const float* __restrict__ W3, const float* __restrict__ b3,
    const float* __restrict__ Wout, const float* __restrict__ bout,
    float* __restrict__ out)
{
    const int g = blockIdx.x;
    const int h = threadIdx.x;
    __shared__ float pld[2 * H];
    __shared__ float hbuf[H];
    const float cc = fmaxf(cnt_c[g], 1.f);
    const float cb = fmaxf(cnt_b[g], 1.f);
    pld[h] = sum_c[g * H + h] / cc;
    pld[H + h] = sum_b[g * H + h] / cb;
    __syncthreads();
    float a1 = b1[h];
    for (int j = 0; j < 2 * H; ++j) a1 = fmaf(pld[j], W1[j * H + h], a1);
    a1 = fmaxf(a1, 0.f);
    __syncthreads();
    hbuf[h] = a1;
    __syncthreads();
    float a2 = b2[h];
    for (int j = 0; j < H; ++j) a2 = fmaf(hbuf[j], W2[j * H + h], a2);
    a2 = fmaxf(a2, 0.f);
    __syncthreads();
    hbuf[h] = a2;
    __syncthreads();
    float a3 = b3[h];
    for (int j = 0; j < H; ++j) a3 = fmaf(hbuf[j], W3[j * H + h], a3);
    a3 = fmaxf(a3, 0.f);
    float p = a3 * Wout[h];
#pragma unroll
    for (int off = 32; off > 0; off >>= 1) p += __shfl_down(p, off, 64);
    if (h == 0) out[g] = p + bout[0];
}

extern "C" void kernel_launch(void* const* d_in, const int* in_sizes, int n_in,
                              void* d_out, int out_size, void* d_ws, size_t ws_size,
                              hipStream_t stream) {
    const float* x_x   = (const float*)d_in[0];
    const float* x_c   = (const float*)d_in[1];
    const float* x_b   = (const float*)d_in[2];
    const float* ea_ac = (const float*)d_in[3];
    const float* ea_cb = (const float*)d_in[4];

    const float* Wk_ac = (const float*)d_in[5];
    const float* Wq_ac = (const float*)d_in[6];
    const float* Wv_ac = (const float*)d_in[7];
    const float* Wskip_ac = (const float*)d_in[8];
    const float* We_ac = (const float*)d_in[9];
    const float* bk_ac = (const float*)d_in[10];
    const float* bq_ac = (const float*)d_in[11];
    const float* bv_ac = (const float*)d_in[12];
    const float* be_ac = (const float*)d_in[13];
    const float* bconv_ac = (const float*)d_in[14];

    const float* Wk_cb = (const float*)d_in[15];
    const float* Wq_cb = (const float*)d_in[16];
    const float* Wv_cb = (const float*)d_in[17];
    const float* Wskip_cb = (const float*)d_in[18];
    const float* We_cb = (const float*)d_in[19];
    const float* bk_cb = (const float*)d_in[20];
    const float* bq_cb = (const float*)d_in[21];
    const float* bv_cb = (const float*)d_in[22];
    const float* be_cb = (const float*)d_in[23];
    const float* bconv_cb = (const float*)d_in[24];

    const float* W1 = (const float*)d_in[25];
    const float* b1 = (const float*)d_in[26];
    const float* W2 = (const float*)d_in[27];
    const float* b2 = (const float*)d_in[28];
    const float* W3 = (const float*)d_in[29];
    const float* b3 = (const float*)d_in[30];
    const float* Wout = (const float*)d_in[31];
    const float* bout = (const float*)d_in[32];

    const int* src_ac = (const int*)d_in[33];
    const int* dst_ac = (const int*)d_in[34];
    const int* src_cb = (const int*)d_in[35];
    const int* dst_cb = (const int*)d_in[36];
    const int* batch_c = (const int*)d_in[37];
    const int* batch_b = (const int*)d_in[38];

    const int Nc = in_sizes[1] / F;
    const int Nb = in_sizes[2] / F;
    const int E1 = in_sizes[33];
    const int E2 = in_sizes[35];
    (void)n_in; (void)out_size; (void)ws_size;

    const int NMAX = (Nc > Nb ? Nc : Nb);
    const int EMAX = (E1 > E2 ? E1 : E2);

    // workspace layout (4B elems):
    // [offsets: NMAX+1][cnt/cursor: NMAX][bsums: 256][ssrc: EMAX][sea: EMAX]
    // [sum_c: 8192][sum_b: 8192][cnt_c: 128][cnt_b: 128]   total ~14MB
    int*   offsets = (int*)d_ws;
    int*   cnt     = offsets + (NMAX + 1);
    int*   bsums   = cnt + NMAX;
    int*   ssrc    = bsums + 256;
    float* sea     = (float*)(ssrc + EMAX);
    float* sum_c   = sea + EMAX;
    float* sum_b   = sum_c + NUM_G * H;
    float* cnt_c   = sum_b + NUM_G * H;
    float* cnt_b   = cnt_c + NUM_G;

    hipMemsetAsync(sum_c, 0, (2 * NUM_G * H + 2 * NUM_G) * sizeof(float), stream);

    const int AGG_BLOCKS = 16384;  // x4 waves/block, grid-stride over dsts

    // ---- relation ('x','a','c') -> updates 'c' ----
    {
        const int n = Nc, E = E1;
        const int nScan = (n + 1023) / 1024;
        hipMemsetAsync(cnt, 0, n * sizeof(int), stream);
        hist_kernel<<<(E + 255) / 256, 256, 0, stream>>>(dst_ac, cnt, E);
        scan_partial<<<nScan, 256, 0, stream>>>(cnt, bsums, n);
        scan_bsums<<<1, 256, 0, stream>>>(bsums, nScan);
        scan_final<<<nScan, 256, 0, stream>>>(cnt, bsums, offsets, n);
        hipMemsetAsync(cnt, 0, n * sizeof(int), stream);  // reuse as cursor
        scatter_kernel<<<(E + 255) / 256, 256, 0, stream>>>(src_ac, dst_ac, ea_ac,
                                                            offsets, cnt, ssrc, sea, E);
        aggregate_kernel<<<AGG_BLOCKS, 256, 0, stream>>>(
            x_x, x_c, offsets, ssrc, sea,
            Wk_ac, bk_ac, Wq_ac, bq_ac, Wv_ac, bv_ac, We_ac, be_ac,
            Wskip_ac, bconv_ac, batch_c, sum_c, n);
    }

    // ---- relation ('c','b','b') -> updates 'b' ----
    {
        const int n = Nb, E = E2;
        const int nScan = (n + 1023) / 1024;
        hipMemsetAsync(cnt, 0, n * sizeof(int), stream);
        hist_kernel<<<(E + 255) / 256, 256, 0, stream>>>(dst_cb, cnt, E);
        scan_partial<<<nScan, 256, 0, stream>>>(cnt, bsums, n);
        scan_bsums<<<1, 256, 0, stream>>>(bsums, nScan);
        scan_final<<<nScan, 256, 0, stream>>>(cnt, bsums, offsets, n);
        hipMemsetAsync(cnt, 0, n * sizeof(int), stream);  // reuse as cursor
        scatter_kernel<<<(E + 255) / 256, 256, 0, stream>>>(src_cb, dst_cb, ea_cb,
                                                            offsets, cnt, ssrc, sea, E);
        aggregate_kernel<<<AGG_BLOCKS, 256, 0, stream>>>(
            x_c, x_b, offsets, ssrc, sea,
            Wk_cb, bk_cb, Wq_cb, bq_cb, Wv_cb, bv_cb, We_cb, be_cb,
            Wskip_cb, bconv_cb, batch_b, sum_b, n);
    }

    count_kernel<<<1, 256, 0, stream>>>(batch_c, Nc, batch_b, Nb, cnt_c, cnt_b);

    mlp_kernel<<<NUM_G, H, 0, stream>>>(
        sum_c, sum_b, cnt_c, cnt_b,
        W1, b1, W2, b2, W3, b3, Wout, bout, (float*)d_out);
}

// Round 3
// 971.243 us; speedup vs baseline: 1.8597x; 1.2423x over previous
//
#include <hip/hip_runtime.h>
#include <math.h>

#define H 64
#define F 16
#define NUM_G 128

__device__ __forceinline__ int lower_bound_i(const int* a, int n, int key) {
    int lo = 0, hi = n;
    while (lo < hi) { int mid = (lo + hi) >> 1; if (a[mid] < key) lo = mid + 1; else hi = mid; }
    return lo;
}

__device__ __forceinline__ float sigmoidf_(float g) {
    return 1.0f / (1.0f + __expf(-g));
}

// ---------------- CSR build: histogram + scan + scatter ----------------

__global__ __launch_bounds__(256) void hist_kernel(const int* __restrict__ dst,
                                                   int* __restrict__ cnt, int E) {
    int i = blockIdx.x * blockDim.x + threadIdx.x;
    if (i < E) atomicAdd(&cnt[dst[i]], 1);
}

__global__ __launch_bounds__(256) void scan_partial(const int* __restrict__ cnt,
                                                    int* __restrict__ bsums, int n) {
    __shared__ int red[256];
    const int b = blockIdx.x, t = threadIdx.x;
    const int base = b * 1024 + t * 4;
    int s = 0;
#pragma unroll
    for (int i = 0; i < 4; ++i) { int idx = base + i; if (idx < n) s += cnt[idx]; }
    red[t] = s;
    __syncthreads();
    for (int off = 128; off > 0; off >>= 1) {
        if (t < off) red[t] += red[t + off];
        __syncthreads();
    }
    if (t == 0) bsums[b] = red[0];
}

__global__ __launch_bounds__(256) void scan_bsums(int* __restrict__ bsums, int nb) {
    __shared__ int sh[256];
    const int t = threadIdx.x;
    sh[t] = (t < nb) ? bsums[t] : 0;
    __syncthreads();
    for (int off = 1; off < 256; off <<= 1) {
        int v = sh[t];
        int add = (t >= off) ? sh[t - off] : 0;
        __syncthreads();
        sh[t] = v + add;
        __syncthreads();
    }
    if (t < nb) bsums[t] = (t == 0) ? 0 : sh[t - 1];
}

__global__ __launch_bounds__(256) void scan_final(const int* __restrict__ cnt,
                                                  const int* __restrict__ bsums,
                                                  int* __restrict__ offsets, int n) {
    __shared__ int red[256];
    const int b = blockIdx.x, t = threadIdx.x;
    const int base = b * 1024 + t * 4;
    int v[4]; int s = 0;
#pragma unroll
    for (int i = 0; i < 4; ++i) { int idx = base + i; v[i] = (idx < n) ? cnt[idx] : 0; s += v[i]; }
    red[t] = s;
    __syncthreads();
    for (int off = 1; off < 256; off <<= 1) {
        int val = red[t];
        int add = (t >= off) ? red[t - off] : 0;
        __syncthreads();
        red[t] = val + add;
        __syncthreads();
    }
    const int ex = (t == 0) ? 0 : red[t - 1];
    int run = bsums[b] + ex;
#pragma unroll
    for (int i = 0; i < 4; ++i) {
        int idx = base + i;
        if (idx < n) offsets[idx] = run;
        run += v[i];
    }
    if (t == 255 && b == gridDim.x - 1) offsets[n] = run;
}

// meta[p] = (src, float_bits(ea)) in dst-sorted order
__global__ __launch_bounds__(256) void scatter_kernel(const int* __restrict__ src,
                                                      const int* __restrict__ dst,
                                                      const float* __restrict__ ea,
                                                      const int* __restrict__ offsets,
                                                      int* __restrict__ cursor,
                                                      int2* __restrict__ meta, int E) {
    int i = blockIdx.x * blockDim.x + threadIdx.x;
    if (i < E) {
        int d = dst[i];
        int p = offsets[d] + atomicAdd(&cursor[d], 1);
        meta[p] = make_int2(src[i], __float_as_int(ea[i]));
    }
}

// ---------------- per-src q/v precompute ----------------
// qv[n][0..63] = q row, qv[n][64..127] = v row
__global__ __launch_bounds__(256) void qv_kernel(
    const float* __restrict__ x,
    const float* __restrict__ Wq, const float* __restrict__ bq,
    const float* __restrict__ Wv, const float* __restrict__ bv,
    float* __restrict__ qv, int N)
{
    const int lane = threadIdx.x & 63;
    float wq[F], wv[F];
#pragma unroll
    for (int f = 0; f < F; ++f) {
        wq[f] = Wq[f * H + lane];
        wv[f] = Wv[f * H + lane];
    }
    const float bqh = bq[lane], bvh = bv[lane];
    const int wave = (blockIdx.x * (blockDim.x >> 6)) + (threadIdx.x >> 6);
    const int nw = gridDim.x * (blockDim.x >> 6);
    for (int n = wave; n < N; n += nw) {
        const float4* xr = (const float4*)(x + (size_t)n * F);
        float q = bqh, v = bvh;
#pragma unroll
        for (int f4 = 0; f4 < F / 4; ++f4) {
            float4 a = xr[f4];
            q = fmaf(a.x, wq[4*f4+0], q); q = fmaf(a.y, wq[4*f4+1], q);
            q = fmaf(a.z, wq[4*f4+2], q); q = fmaf(a.w, wq[4*f4+3], q);
            v = fmaf(a.x, wv[4*f4+0], v); v = fmaf(a.y, wv[4*f4+1], v);
            v = fmaf(a.z, wv[4*f4+2], v); v = fmaf(a.w, wv[4*f4+3], v);
        }
        float* row = qv + (size_t)n * 128;
        row[lane] = q;
        row[64 + lane] = v;
    }
}

// ---------------- per-dst gather-reduce with precomputed q/v ----------------
__global__ __launch_bounds__(256) void aggregate_pre_kernel(
    const float* __restrict__ x_dst, const float* __restrict__ qv,
    const int* __restrict__ offsets, const int2* __restrict__ meta,
    const float* __restrict__ Wk, const float* __restrict__ bk,
    const float* __restrict__ We, const float* __restrict__ be,
    const float* __restrict__ Wskip, const float* __restrict__ bconv,
    const int* __restrict__ batch, float* __restrict__ pool_sum, int Ndst)
{
    const int lane = threadIdx.x & 63;
    float wk[F], wsk[F];
#pragma unroll
    for (int f = 0; f < F; ++f) {
        wk[f] = Wk[f * H + lane];
        wsk[f] = Wskip[f * H + lane];
    }
    const float bkh = bk[lane], bch = bconv[lane];
    const float weh = We[lane], beh = be[lane];
    const int wave = (blockIdx.x * (blockDim.x >> 6)) + (threadIdx.x >> 6);
    const int nw = gridDim.x * (blockDim.x >> 6);
    for (int d = wave; d < Ndst; d += nw) {
        const float4* xd = (const float4*)(x_dst + (size_t)d * F);
        float k = bkh, sk = bch;
#pragma unroll
        for (int f4 = 0; f4 < F / 4; ++f4) {
            float4 b = xd[f4];
            k = fmaf(b.x, wk[4*f4+0], k); k = fmaf(b.y, wk[4*f4+1], k);
            k = fmaf(b.z, wk[4*f4+2], k); k = fmaf(b.w, wk[4*f4+3], k);
            sk = fmaf(b.x, wsk[4*f4+0], sk); sk = fmaf(b.y, wsk[4*f4+1], sk);
            sk = fmaf(b.z, wsk[4*f4+2], sk); sk = fmaf(b.w, wsk[4*f4+3], sk);
        }
        const int p0 = offsets[d];
        const int p1 = offsets[d + 1];
        float acc = 0.f;
        int p = p0;
        for (; p + 4 <= p1; p += 4) {
            int2 m0 = meta[p], m1 = meta[p + 1], m2 = meta[p + 2], m3 = meta[p + 3];
            const float* r0 = qv + (size_t)m0.x * 128;
            const float* r1 = qv + (size_t)m1.x * 128;
            const float* r2 = qv + (size_t)m2.x * 128;
            const float* r3 = qv + (size_t)m3.x * 128;
            float q0 = r0[lane], u0 = r0[64 + lane];
            float q1 = r1[lane], u1 = r1[64 + lane];
            float q2 = r2[lane], u2 = r2[64 + lane];
            float q3 = r3[lane], u3 = r3[64 + lane];
            float e0 = fmaf(__int_as_float(m0.y), weh, beh);
            float e1 = fmaf(__int_as_float(m1.y), weh, beh);
            float e2 = fmaf(__int_as_float(m2.y), weh, beh);
            float e3 = fmaf(__int_as_float(m3.y), weh, beh);
            acc = fmaf(sigmoidf_(fmaf(2.f, e0, k + q0)), u0 + e0, acc);
            acc = fmaf(sigmoidf_(fmaf(2.f, e1, k + q1)), u1 + e1, acc);
            acc = fmaf(sigmoidf_(fmaf(2.f, e2, k + q2)), u2 + e2, acc);
            acc = fmaf(sigmoidf_(fmaf(2.f, e3, k + q3)), u3 + e3, acc);
        }
        for (; p < p1; ++p) {
            int2 m = meta[p];
            const float* r = qv + (size_t)m.x * 128;
            float q = r[lane], u = r[64 + lane];
            float e = fmaf(__int_as_float(m.y), weh, beh);
            acc = fmaf(sigmoidf_(fmaf(2.f, e, k + q)), u + e, acc);
        }
        const float hval = fmaxf(acc + sk, 0.f);
        atomicAdd(&pool_sum[(size_t)batch[d] * H + lane], hval);
    }
}

// ---------------- fallback (small ws): recompute q/v per edge ----------------
__global__ __launch_bounds__(256) void aggregate_kernel(
    const float* __restrict__ x_src, const float* __restrict__ x_dst,
    const int* __restrict__ offsets, const int2* __restrict__ meta,
    const float* __restrict__ Wk, const float* __restrict__ bk,
    const float* __restrict__ Wq, const float* __restrict__ bq,
    const float* __restrict__ Wv, const float* __restrict__ bv,
    const float* __restrict__ We, const float* __restrict__ be,
    const float* __restrict__ Wskip, const float* __restrict__ bconv,
    const int* __restrict__ batch, float* __restrict__ pool_sum, int Ndst)
{
    const int lane = threadIdx.x & 63;
    float wq[F], wv[F], wk[F], wsk[F];
#pragma unroll
    for (int f = 0; f < F; ++f) {
        wq[f] = Wq[f * H + lane];
        wv[f] = Wv[f * H + lane];
        wk[f] = Wk[f * H + lane];
        wsk[f] = Wskip[f * H + lane];
    }
    const float bqh = bq[lane], bvh = bv[lane], bkh = bk[lane], bch = bconv[lane];
    const float weh = We[lane], beh = be[lane];
    const int wave = (blockIdx.x * (blockDim.x >> 6)) + (threadIdx.x >> 6);
    const int nw = gridDim.x * (blockDim.x >> 6);
    for (int d = wave; d < Ndst; d += nw) {
        const float4* xd = (const float4*)(x_dst + (size_t)d * F);
        float k = bkh, sk = bch;
#pragma unroll
        for (int f4 = 0; f4 < F / 4; ++f4) {
            float4 b = xd[f4];
            k = fmaf(b.x, wk[4*f4+0], k); k = fmaf(b.y, wk[4*f4+1], k);
            k = fmaf(b.z, wk[4*f4+2], k); k = fmaf(b.w, wk[4*f4+3], k);
            sk = fmaf(b.x, wsk[4*f4+0], sk); sk = fmaf(b.y, wsk[4*f4+1], sk);
            sk = fmaf(b.z, wsk[4*f4+2], sk); sk = fmaf(b.w, wsk[4*f4+3], sk);
        }
        float acc = 0.f;
        const int p0 = offsets[d];
        const int p1 = offsets[d + 1];
        for (int p = p0; p < p1; ++p) {
            int2 m = meta[p];
            const float4* xs = (const float4*)(x_src + (size_t)m.x * F);
            float q = bqh, v = bvh;
#pragma unroll
            for (int f4 = 0; f4 < F / 4; ++f4) {
                float4 a = xs[f4];
                q = fmaf(a.x, wq[4*f4+0], q); q = fmaf(a.y, wq[4*f4+1], q);
                q = fmaf(a.z, wq[4*f4+2], q); q = fmaf(a.w, wq[4*f4+3], q);
                v = fmaf(a.x, wv[4*f4+0], v); v = fmaf(a.y, wv[4*f4+1], v);
                v = fmaf(a.z, wv[4*f4+2], v); v = fmaf(a.w, wv[4*f4+3], v);
            }
            float e = fmaf(__int_as_float(m.y), weh, beh);
            acc = fmaf(sigmoidf_(fmaf(2.f, e, k + q)), v + e, acc);
        }
        const float hval = fmaxf(acc + sk, 0.f);
        atomicAdd(&pool_sum[(size_t)batch[d] * H + lane], hval);
    }
}

__global__ void count_kernel(const int* __restrict__ batch_c, int Nc,
                             const int* __restrict__ batch_b, int Nb,
                             float* __restrict__ cnt_c, float* __restrict__ cnt_b)
{
    int t = threadIdx.x;
    if (t < NUM_G) {
        int lo = lower_bound_i(batch_c, Nc, t);
        int hi = lower_bound_i(batch_c, Nc, t + 1);
        cnt_c[t] = (float)(hi - lo);
    } else if (t < 2 * NUM_G) {
        int g = t - NUM_G;
        int lo = lower_bound_i(batch_b, Nb, g);
        int hi = lower_bound_i(batch_b, Nb, g + 1);
        cnt_b[g] = (float)(hi - lo);
    }
}

__global__ __launch_bounds__(64) void mlp_kernel(
    const float* __restrict__ sum_c, const float* __restrict__ sum_b,
    const float* __restrict__ cnt_c, const float* __restrict__ cnt_b,
    const float* __restrict__ W1, const float* __restrict__ b1,
    const float* __restrict__ W2, const float* __restrict__ b2,
    const float* __restrict__ W3, const float* __restrict__ b3,
    const float* __restrict__ Wout, const float* __restrict__ bout,
    float* __restrict__ out)
{
    const int g = blockIdx.x;
    const int h = threadIdx.x;
    __shared__ float pld[2 * H];
    __shared__ float hbuf[H];
    const float cc = fmaxf(cnt_c[g], 1.f);
    const float cb = fmaxf(cnt_b[g], 1.f);
    pld[h] = sum_c[g * H + h] / cc;
    pld[H + h] = sum_b[g * H + h] / cb;
    __syncthreads();
    float a1 = b1[h];
    for (int j = 0; j < 2 * H; ++j) a1 = fmaf(pld[j], W1[j * H + h], a1);
    a1 = fmaxf(a1, 0.f);
    __syncthreads();
    hbuf[h] = a1;
    __syncthreads();
    float a2 = b2[h];
    for (int j = 0; j < H; ++j) a2 = fmaf(hbuf[j], W2[j * H + h], a2);
    a2 = fmaxf(a2, 0.f);
    __syncthreads();
    hbuf[h] = a2;
    __syncthreads();
    float a3 = b3[h];
    for (int j = 0; j < H; ++j) a3 = fmaf(hbuf[j], W3[j * H + h], a3);
    a3 = fmaxf(a3, 0.f);
    float p = a3 * Wout[h];
#pragma unroll
    for (int off = 32; off > 0; off >>= 1) p += __shfl_down(p, off, 64);
    if (h == 0) out[g] = p + bout[0];
}

extern "C" void kernel_launch(void* const* d_in, const int* in_sizes, int n_in,
                              void* d_out, int out_size, void* d_ws, size_t ws_size,
                              hipStream_t stream) {
    const float* x_x   = (const float*)d_in[0];
    const float* x_c   = (const float*)d_in[1];
    const float* x_b   = (const float*)d_in[2];
    const float* ea_ac = (const float*)d_in[3];
    const float* ea_cb = (const float*)d_in[4];

    const float* Wk_ac = (const float*)d_in[5];
    const float* Wq_ac = (const float*)d_in[6];
    const float* Wv_ac = (const float*)d_in[7];
    const float* Wskip_ac = (const float*)d_in[8];
    const float* We_ac = (const float*)d_in[9];
    const float* bk_ac = (const float*)d_in[10];
    const float* bq_ac = (const float*)d_in[11];
    const float* bv_ac = (const float*)d_in[12];
    const float* be_ac = (const float*)d_in[13];
    const float* bconv_ac = (const float*)d_in[14];

    const float* Wk_cb = (const float*)d_in[15];
    const float* Wq_cb = (const float*)d_in[16];
    const float* Wv_cb = (const float*)d_in[17];
    const float* Wskip_cb = (const float*)d_in[18];
    const float* We_cb = (const float*)d_in[19];
    const float* bk_cb = (const float*)d_in[20];
    const float* bq_cb = (const float*)d_in[21];
    const float* bv_cb = (const float*)d_in[22];
    const float* be_cb = (const float*)d_in[23];
    const float* bconv_cb = (const float*)d_in[24];

    const float* W1 = (const float*)d_in[25];
    const float* b1 = (const float*)d_in[26];
    const float* W2 = (const float*)d_in[27];
    const float* b2 = (const float*)d_in[28];
    const float* W3 = (const float*)d_in[29];
    const float* b3 = (const float*)d_in[30];
    const float* Wout = (const float*)d_in[31];
    const float* bout = (const float*)d_in[32];

    const int* src_ac = (const int*)d_in[33];
    const int* dst_ac = (const int*)d_in[34];
    const int* src_cb = (const int*)d_in[35];
    const int* dst_cb = (const int*)d_in[36];
    const int* batch_c = (const int*)d_in[37];
    const int* batch_b = (const int*)d_in[38];

    const int Nx = in_sizes[0] / F;
    const int Nc = in_sizes[1] / F;
    const int Nb = in_sizes[2] / F;
    const int E1 = in_sizes[33];
    const int E2 = in_sizes[35];
    (void)n_in; (void)out_size;

    const int NMAX = (Nc > Nb ? Nc : Nb);
    const int EMAX = (E1 > E2 ? E1 : E2);
    const int SRCMAX = (Nx > Nc ? Nx : Nc);

    // workspace layout (4B units):
    // [offsets: NMAX+1][cnt: NMAX][bsums: 256][meta: 2*EMAX]
    // [sum_c: 8192][sum_b: 8192][cnt_c: 128][cnt_b: 128][qv: SRCMAX*128 (optional)]
    int*   offsets = (int*)d_ws;
    int*   cnt     = offsets + (NMAX + 1);
    int*   bsums   = cnt + NMAX;
    int2*  meta    = (int2*)(bsums + 256);
    float* sum_c   = (float*)(meta + EMAX);
    float* sum_b   = sum_c + NUM_G * H;
    float* cnt_c   = sum_b + NUM_G * H;
    float* cnt_b   = cnt_c + NUM_G;
    float* qv      = cnt_b + NUM_G;
    const size_t need = (size_t)(qv - (float*)d_ws) * 4 + (size_t)SRCMAX * 128 * 4;
    const bool usePre = (ws_size >= need);

    hipMemsetAsync(sum_c, 0, (2 * NUM_G * H + 2 * NUM_G) * sizeof(float), stream);

    const int AGG_BLOCKS = 16384;

    for (int rel = 0; rel < 2; ++rel) {
        const int n = rel ? Nb : Nc;
        const int E = rel ? E2 : E1;
        const int Ns = rel ? Nc : Nx;
        const int* srcA = rel ? src_cb : src_ac;
        const int* dstA = rel ? dst_cb : dst_ac;
        const float* eaA = rel ? ea_cb : ea_ac;
        const float* xs = rel ? x_c : x_x;
        const float* xd = rel ? x_b : x_c;
        const float* Wk = rel ? Wk_cb : Wk_ac; const float* bk = rel ? bk_cb : bk_ac;
        const float* Wq = rel ? Wq_cb : Wq_ac; const float* bq = rel ? bq_cb : bq_ac;
        const float* Wv = rel ? Wv_cb : Wv_ac; const float* bv = rel ? bv_cb : bv_ac;
        const float* We = rel ? We_cb : We_ac; const float* be = rel ? be_cb : be_ac;
        const float* Wsk = rel ? Wskip_cb : Wskip_ac;
        const float* bcv = rel ? bconv_cb : bconv_ac;
        const int* batch = rel ? batch_b : batch_c;
        float* psum = rel ? sum_b : sum_c;

        const int nScan = (n + 1023) / 1024;
        hipMemsetAsync(cnt, 0, n * sizeof(int), stream);
        hist_kernel<<<(E + 255) / 256, 256, 0, stream>>>(dstA, cnt, E);
        scan_partial<<<nScan, 256, 0, stream>>>(cnt, bsums, n);
        scan_bsums<<<1, 256, 0, stream>>>(bsums, nScan);
        scan_final<<<nScan, 256, 0, stream>>>(cnt, bsums, offsets, n);
        hipMemsetAsync(cnt, 0, n * sizeof(int), stream);  // reuse as cursor
        scatter_kernel<<<(E + 255) / 256, 256, 0, stream>>>(srcA, dstA, eaA,
                                                            offsets, cnt, meta, E);
        if (usePre) {
            qv_kernel<<<4096, 256, 0, stream>>>(xs, Wq, bq, Wv, bv, qv, Ns);
            aggregate_pre_kernel<<<AGG_BLOCKS, 256, 0, stream>>>(
                xd, qv, offsets, meta, Wk, bk, We, be, Wsk, bcv, batch, psum, n);
        } else {
            aggregate_kernel<<<AGG_BLOCKS, 256, 0, stream>>>(
                xs, xd, offsets, meta, Wk, bk, Wq, bq, Wv, bv, We, be,
                Wsk, bcv, batch, psum, n);
        }
    }

    count_kernel<<<1, 256, 0, stream>>>(batch_c, Nc, batch_b, Nb, cnt_c, cnt_b);

    mlp_kernel<<<NUM_G, H, 0, stream>>>(
        sum_c, sum_b, cnt_c, cnt_b,
        W1, b1, W2, b2, W3, b3, Wout, bout, (float*)d_out);
}

// Round 4
// 933.925 us; speedup vs baseline: 1.9340x; 1.0400x over previous
//
#include <hip/hip_runtime.h>
#include <math.h>

#define H 64
#define F 16
#define NUM_G 128
#define DPW 8   // dsts per wave chunk

__device__ __forceinline__ int lower_bound_i(const int* a, int n, int key) {
    int lo = 0, hi = n;
    while (lo < hi) { int mid = (lo + hi) >> 1; if (a[mid] < key) lo = mid + 1; else hi = mid; }
    return lo;
}

__device__ __forceinline__ float sigmoidf_(float g) {
    return 1.0f / (1.0f + __expf(-g));
}

// ---------------- CSR build ----------------

// add 1 to cntBase[dst[i]] (cntBase pre-offset for relation)
__global__ __launch_bounds__(256) void hist_kernel(const int* __restrict__ dst,
                                                   int* __restrict__ cntBase, int E) {
    int i = blockIdx.x * blockDim.x + threadIdx.x;
    if (i < E) atomicAdd(&cntBase[dst[i]], 1);
}

// 2048 elems per block (256 thr x 8)
__global__ __launch_bounds__(256) void scan_partial(const int* __restrict__ cnt,
                                                    int* __restrict__ bsums, int n) {
    __shared__ int red[256];
    const int b = blockIdx.x, t = threadIdx.x;
    const int base = b * 2048 + t * 8;
    int s = 0;
#pragma unroll
    for (int i = 0; i < 8; ++i) { int idx = base + i; if (idx < n) s += cnt[idx]; }
    red[t] = s;
    __syncthreads();
    for (int off = 128; off > 0; off >>= 1) {
        if (t < off) red[t] += red[t + off];
        __syncthreads();
    }
    if (t == 0) bsums[b] = red[0];
}

__global__ __launch_bounds__(256) void scan_bsums(int* __restrict__ bsums, int nb) {
    __shared__ int sh[256];
    const int t = threadIdx.x;
    sh[t] = (t < nb) ? bsums[t] : 0;
    __syncthreads();
    for (int off = 1; off < 256; off <<= 1) {
        int v = sh[t];
        int add = (t >= off) ? sh[t - off] : 0;
        __syncthreads();
        sh[t] = v + add;
        __syncthreads();
    }
    if (t < nb) bsums[t] = (t == 0) ? 0 : sh[t - 1];
}

__global__ __launch_bounds__(256) void scan_final(const int* __restrict__ cnt,
                                                  const int* __restrict__ bsums,
                                                  int* __restrict__ offsets, int n) {
    __shared__ int red[256];
    const int b = blockIdx.x, t = threadIdx.x;
    const int base = b * 2048 + t * 8;
    int v[8]; int s = 0;
#pragma unroll
    for (int i = 0; i < 8; ++i) { int idx = base + i; v[i] = (idx < n) ? cnt[idx] : 0; s += v[i]; }
    red[t] = s;
    __syncthreads();
    for (int off = 1; off < 256; off <<= 1) {
        int val = red[t];
        int add = (t >= off) ? red[t - off] : 0;
        __syncthreads();
        red[t] = val + add;
        __syncthreads();
    }
    const int ex = (t == 0) ? 0 : red[t - 1];
    int run = bsums[b] + ex;
#pragma unroll
    for (int i = 0; i < 8; ++i) {
        int idx = base + i;
        if (idx < n) offsets[idx] = run;
        run += v[i];
    }
    if (t == 255 && b == gridDim.x - 1) offsets[n] = run;
}

// meta[p] = (src+srcOff, float_bits(ea)); offs/cur pre-offset for relation
__global__ __launch_bounds__(256) void scatter_kernel(const int* __restrict__ src,
                                                      const int* __restrict__ dst,
                                                      const float* __restrict__ ea,
                                                      const int* __restrict__ offsBase,
                                                      int* __restrict__ curBase,
                                                      int2* __restrict__ meta, int E,
                                                      int srcOff) {
    int i = blockIdx.x * blockDim.x + threadIdx.x;
    if (i < E) {
        int d = dst[i];
        int p = offsBase[d] + atomicAdd(&curBase[d], 1);
        meta[p] = make_int2(src[i] + srcOff, __float_as_int(ea[i]));
    }
}

// ---------------- per-src q/v precompute (interleaved float2) ----------------
__global__ __launch_bounds__(256) void qv_kernel(
    const float* __restrict__ x,
    const float* __restrict__ Wq, const float* __restrict__ bq,
    const float* __restrict__ Wv, const float* __restrict__ bv,
    float2* __restrict__ qvBase, int N)
{
    const int lane = threadIdx.x & 63;
    float wq[F], wv[F];
#pragma unroll
    for (int f = 0; f < F; ++f) {
        wq[f] = Wq[f * H + lane];
        wv[f] = Wv[f * H + lane];
    }
    const float bqh = bq[lane], bvh = bv[lane];
    const int wave = (blockIdx.x * (blockDim.x >> 6)) + (threadIdx.x >> 6);
    const int nw = gridDim.x * (blockDim.x >> 6);
    for (int n = wave; n < N; n += nw) {
        const float4* xr = (const float4*)(x + (size_t)n * F);
        float q = bqh, v = bvh;
#pragma unroll
        for (int f4 = 0; f4 < F / 4; ++f4) {
            float4 a = xr[f4];
            q = fmaf(a.x, wq[4*f4+0], q); q = fmaf(a.y, wq[4*f4+1], q);
            q = fmaf(a.z, wq[4*f4+2], q); q = fmaf(a.w, wq[4*f4+3], q);
            v = fmaf(a.x, wv[4*f4+0], v); v = fmaf(a.y, wv[4*f4+1], v);
            v = fmaf(a.z, wv[4*f4+2], v); v = fmaf(a.w, wv[4*f4+3], v);
        }
        qvBase[(size_t)n * 64 + lane] = make_float2(q, v);
    }
}

// ---------------- chunked streaming aggregate ----------------
struct RelP {
    const float* x_dst;
    const float *Wk, *bk, *We, *be, *Wsk, *bcv;
    const int* batch;
    float* psum;
    int Ndst;
    int offBase;  // index offset into shared `offsets` array
    int qvOff;    // subtract from meta src id to index qv rows
};

__global__ __launch_bounds__(256) void aggregate_chunks(
    RelP P0, RelP P1, const float2* __restrict__ qv,
    const int* __restrict__ offsets, const int2* __restrict__ meta,
    int nChunk0, int chunkHi)
{
    const int lane = threadIdx.x & 63;
    const int cid = blockIdx.x * (blockDim.x >> 6) + (threadIdx.x >> 6);
    if (cid >= chunkHi) return;
    const bool r1 = (cid >= nChunk0);
    const RelP P = r1 ? P1 : P0;
    const int dLo = (r1 ? cid - nChunk0 : cid) * DPW;
    if (dLo >= P.Ndst) return;
    const int dHi = (dLo + DPW < P.Ndst) ? dLo + DPW : P.Ndst;

    float wk[F], wsk[F];
#pragma unroll
    for (int f = 0; f < F; ++f) {
        wk[f] = P.Wk[f * H + lane];
        wsk[f] = P.Wsk[f * H + lane];
    }
    const float bkh = P.bk[lane], bch = P.bcv[lane];
    const float weh = P.We[lane], beh = P.be[lane];

#define LOADK(DL)                                                            \
    {                                                                        \
        const float4* xr = (const float4*)(P.x_dst + (size_t)(DL) * F);      \
        k = bkh; sk = bch;                                                   \
        _Pragma("unroll")                                                    \
        for (int f4 = 0; f4 < F / 4; ++f4) {                                 \
            float4 b = xr[f4];                                               \
            k = fmaf(b.x, wk[4*f4+0], k); k = fmaf(b.y, wk[4*f4+1], k);      \
            k = fmaf(b.z, wk[4*f4+2], k); k = fmaf(b.w, wk[4*f4+3], k);      \
            sk = fmaf(b.x, wsk[4*f4+0], sk); sk = fmaf(b.y, wsk[4*f4+1], sk);\
            sk = fmaf(b.z, wsk[4*f4+2], sk); sk = fmaf(b.w, wsk[4*f4+3], sk);\
        }                                                                    \
    }

#define FLUSH(DL)                                                            \
    {                                                                        \
        float hv = fmaxf(acc + sk, 0.f);                                     \
        atomicAdd(&P.psum[(size_t)P.batch[DL] * H + lane], hv);              \
    }

    int dl = dl = dLo;
    int p     = __builtin_amdgcn_readfirstlane(offsets[P.offBase + dLo]);
    int pend  = __builtin_amdgcn_readfirstlane(offsets[P.offBase + dLo + 1]);
    const int pstop = __builtin_amdgcn_readfirstlane(offsets[P.offBase + dHi]);
    float k, sk;
    LOADK(dl);
    float acc = 0.f;

    while (p < pstop) {
        int nb = pstop - p; if (nb > 8) nb = 8;
        int2 m[8]; float2 r[8];
#pragma unroll
        for (int j = 0; j < 8; ++j) if (j < nb) m[j] = meta[p + j];
#pragma unroll
        for (int j = 0; j < 8; ++j) if (j < nb)
            r[j] = qv[(size_t)(m[j].x - P.qvOff) * 64 + lane];
#pragma unroll
        for (int j = 0; j < 8; ++j) {
            if (j < nb) {
                while (p + j >= pend) {   // wave-uniform dst boundary
                    FLUSH(dl);
                    ++dl;
                    LOADK(dl);
                    acc = 0.f;
                    pend = __builtin_amdgcn_readfirstlane(offsets[P.offBase + dl + 1]);
                }
                float e = fmaf(__int_as_float(m[j].y), weh, beh);
                float g = k + r[j].x + 2.0f * e;
                acc = fmaf(sigmoidf_(g), r[j].y + e, acc);
            }
        }
        p += nb;
    }
    // flush current dst, then any trailing empty dsts
    FLUSH(dl);
    ++dl;
    while (dl < dHi) {
        LOADK(dl);
        acc = 0.f;
        FLUSH(dl);
        ++dl;
    }
#undef LOADK
#undef FLUSH
}

// ---------------- pooling counts + MLP ----------------
__global__ void count_kernel(const int* __restrict__ batch_c, int Nc,
                             const int* __restrict__ batch_b, int Nb,
                             float* __restrict__ cnt_c, float* __restrict__ cnt_b)
{
    int t = threadIdx.x;
    if (t < NUM_G) {
        int lo = lower_bound_i(batch_c, Nc, t);
        int hi = lower_bound_i(batch_c, Nc, t + 1);
        cnt_c[t] = (float)(hi - lo);
    } else if (t < 2 * NUM_G) {
        int g = t - NUM_G;
        int lo = lower_bound_i(batch_b, Nb, g);
        int hi = lower_bound_i(batch_b, Nb, g + 1);
        cnt_b[g] = (float)(hi - lo);
    }
}

__global__ __launch_bounds__(64) void mlp_kernel(
    const float* __restrict__ sum_c, const float* __restrict__ sum_b,
    const float* __restrict__ cnt_c, const float* __restrict__ cnt_b,
    const float* __restrict__ W1, const float* __restrict__ b1,
    const float* __restrict__ W2, const float* __restrict__ b2,
    const float* __restrict__ W3, const float* __restrict__ b3,
    const float* __restrict__ Wout, const float* __restrict__ bout,
    float* __restrict__ out)
{
    const int g = blockIdx.x;
    const int h = threadIdx.x;
    __shared__ float pld[2 * H];
    __shared__ float hbuf[H];
    const float cc = fmaxf(cnt_c[g], 1.f);
    const float cb = fmaxf(cnt_b[g], 1.f);
    pld[h] = sum_c[g * H + h] / cc;
    pld[H + h] = sum_b[g * H + h] / cb;
    __syncthreads();
    float a1 = b1[h];
    for (int j = 0; j < 2 * H; ++j) a1 = fmaf(pld[j], W1[j * H + h], a1);
    a1 = fmaxf(a1, 0.f);
    __syncthreads();
    hbuf[h] = a1;
    __syncthreads();
    float a2 = b2[h];
    for (int j = 0; j < H; ++j) a2 = fmaf(hbuf[j], W2[j * H + h], a2);
    a2 = fmaxf(a2, 0.f);
    __syncthreads();
    hbuf[h] = a2;
    __syncthreads();
    float a3 = b3[h];
    for (int j = 0; j < H; ++j) a3 = fmaf(hbuf[j], W3[j * H + h], a3);
    a3 = fmaxf(a3, 0.f);
    float p = a3 * Wout[h];
#pragma unroll
    for (int off = 32; off > 0; off >>= 1) p += __shfl_down(p, off, 64);
    if (h == 0) out[g] = p + bout[0];
}

extern "C" void kernel_launch(void* const* d_in, const int* in_sizes, int n_in,
                              void* d_out, int out_size, void* d_ws, size_t ws_size,
                              hipStream_t stream) {
    const float* x_x   = (const float*)d_in[0];
    const float* x_c   = (const float*)d_in[1];
    const float* x_b   = (const float*)d_in[2];
    const float* ea_ac = (const float*)d_in[3];
    const float* ea_cb = (const float*)d_in[4];

    const float* Wk_ac = (const float*)d_in[5];
    const float* Wq_ac = (const float*)d_in[6];
    const float* Wv_ac = (const float*)d_in[7];
    const float* Wskip_ac = (const float*)d_in[8];
    const float* We_ac = (const float*)d_in[9];
    const float* bk_ac = (const float*)d_in[10];
    const float* bq_ac = (const float*)d_in[11];
    const float* bv_ac = (const float*)d_in[12];
    const float* be_ac = (const float*)d_in[13];
    const float* bconv_ac = (const float*)d_in[14];

    const float* Wk_cb = (const float*)d_in[15];
    const float* Wq_cb = (const float*)d_in[16];
    const float* Wv_cb = (const float*)d_in[17];
    const float* Wskip_cb = (const float*)d_in[18];
    const float* We_cb = (const float*)d_in[19];
    const float* bk_cb = (const float*)d_in[20];
    const float* bq_cb = (const float*)d_in[21];
    const float* bv_cb = (const float*)d_in[22];
    const float* be_cb = (const float*)d_in[23];
    const float* bconv_cb = (const float*)d_in[24];

    const float* W1 = (const float*)d_in[25];
    const float* b1 = (const float*)d_in[26];
    const float* W2 = (const float*)d_in[27];
    const float* b2 = (const float*)d_in[28];
    const float* W3 = (const float*)d_in[29];
    const float* b3 = (const float*)d_in[30];
    const float* Wout = (const float*)d_in[31];
    const float* bout = (const float*)d_in[32];

    const int* src_ac = (const int*)d_in[33];
    const int* dst_ac = (const int*)d_in[34];
    const int* src_cb = (const int*)d_in[35];
    const int* dst_cb = (const int*)d_in[36];
    const int* batch_c = (const int*)d_in[37];
    const int* batch_b = (const int*)d_in[38];

    const int Nx = in_sizes[0] / F;
    const int Nc = in_sizes[1] / F;
    const int Nb = in_sizes[2] / F;
    const int E1 = in_sizes[33];
    const int E2 = in_sizes[35];
    (void)n_in; (void)out_size;

    const int nC0 = (Nc + DPW - 1) / DPW;
    const int nC1 = (Nb + DPW - 1) / DPW;

    // ---- workspace sizing: path A (fused, concat) vs path C (per-rel) ----
    const int NT = Nc + Nb;
    const size_t ET = (size_t)E1 + E2;
    const int NMAX = (Nc > Nb ? Nc : Nb);
    const int EMAX = (E1 > E2 ? E1 : E2);
    const int SRCMAX = (Nx > Nc ? Nx : Nc);
    const size_t SUMS = 2 * NUM_G * H + 2 * NUM_G;

    size_t qvStartA = 2 * ET + (size_t)(NT + 1) + NT + 256 + SUMS;
    qvStartA = (qvStartA + 1) & ~(size_t)1;
    const size_t needA = (qvStartA + (size_t)(Nx + Nc) * 128) * 4;

    size_t qvStartC = 2 * (size_t)EMAX + (size_t)(NMAX + 1) + NMAX + 256 + SUMS;
    qvStartC = (qvStartC + 1) & ~(size_t)1;

    const bool pathA = (ws_size >= needA);

    int* ws = (int*)d_ws;
    const size_t metaN = pathA ? 2 * ET : 2 * (size_t)EMAX;
    const int nOff = pathA ? NT : NMAX;
    int2*  meta    = (int2*)ws;
    int*   offsets = ws + metaN;
    int*   cnt     = offsets + (nOff + 1);
    int*   bsums   = cnt + nOff;
    float* sum_c   = (float*)(bsums + 256);
    float* sum_b   = sum_c + NUM_G * H;
    float* cnt_c   = sum_b + NUM_G * H;
    float* cnt_b   = cnt_c + NUM_G;
    float2* qv     = (float2*)(ws + (pathA ? qvStartA : qvStartC));

    hipMemsetAsync(sum_c, 0, SUMS * sizeof(float), stream);

    RelP P0, P1;
    P0.x_dst = x_c; P0.Wk = Wk_ac; P0.bk = bk_ac; P0.We = We_ac; P0.be = be_ac;
    P0.Wsk = Wskip_ac; P0.bcv = bconv_ac; P0.batch = batch_c; P0.psum = sum_c;
    P0.Ndst = Nc; P0.offBase = 0; P0.qvOff = 0;
    P1.x_dst = x_b; P1.Wk = Wk_cb; P1.bk = bk_cb; P1.We = We_cb; P1.be = be_cb;
    P1.Wsk = Wskip_cb; P1.bcv = bconv_cb; P1.batch = batch_b; P1.psum = sum_b;
    P1.Ndst = Nb; P1.offBase = pathA ? Nc : 0; P1.qvOff = 0;

    if (pathA) {
        // fused CSR over concatenated dst space [0, Nc+Nb)
        const int nScan = (NT + 2047) / 2048;
        hipMemsetAsync(cnt, 0, NT * sizeof(int), stream);
        hist_kernel<<<(E1 + 255) / 256, 256, 0, stream>>>(dst_ac, cnt, E1);
        hist_kernel<<<(E2 + 255) / 256, 256, 0, stream>>>(dst_cb, cnt + Nc, E2);
        scan_partial<<<nScan, 256, 0, stream>>>(cnt, bsums, NT);
        scan_bsums<<<1, 256, 0, stream>>>(bsums, nScan);
        scan_final<<<nScan, 256, 0, stream>>>(cnt, bsums, offsets, NT);
        hipMemsetAsync(cnt, 0, NT * sizeof(int), stream);
        scatter_kernel<<<(E1 + 255) / 256, 256, 0, stream>>>(
            src_ac, dst_ac, ea_ac, offsets, cnt, meta, E1, 0);
        scatter_kernel<<<(E2 + 255) / 256, 256, 0, stream>>>(
            src_cb, dst_cb, ea_cb, offsets + Nc, cnt + Nc, meta, E2, Nx);
        // qv rows: [0,Nx) from x_x/rel0 weights, [Nx,Nx+Nc) from x_c/rel1 weights
        qv_kernel<<<2048, 256, 0, stream>>>(x_x, Wq_ac, bq_ac, Wv_ac, bv_ac, qv, Nx);
        qv_kernel<<<2048, 256, 0, stream>>>(x_c, Wq_cb, bq_cb, Wv_cb, bv_cb,
                                            qv + (size_t)Nx * 64, Nc);
        const int nW = nC0 + nC1;
        aggregate_chunks<<<(nW + 3) / 4, 256, 0, stream>>>(
            P0, P1, qv, offsets, meta, nC0, nW);
    } else {
        // per-relation (proven ~65MB layout)
        for (int rel = 0; rel < 2; ++rel) {
            const int n = rel ? Nb : Nc;
            const int E = rel ? E2 : E1;
            const int Ns = rel ? Nc : Nx;
            const int* srcA = rel ? src_cb : src_ac;
            const int* dstA = rel ? dst_cb : dst_ac;
            const float* eaA = rel ? ea_cb : ea_ac;
            const float* xs = rel ? x_c : x_x;
            const float* Wq = rel ? Wq_cb : Wq_ac; const float* bq = rel ? bq_cb : bq_ac;
            const float* Wv = rel ? Wv_cb : Wv_ac; const float* bv = rel ? bv_cb : bv_ac;
            const int nScan = (n + 2047) / 2048;
            hipMemsetAsync(cnt, 0, n * sizeof(int), stream);
            hist_kernel<<<(E + 255) / 256, 256, 0, stream>>>(dstA, cnt, E);
            scan_partial<<<nScan, 256, 0, stream>>>(cnt, bsums, n);
            scan_bsums<<<1, 256, 0, stream>>>(bsums, nScan);
            scan_final<<<nScan, 256, 0, stream>>>(cnt, bsums, offsets, n);
            hipMemsetAsync(cnt, 0, n * sizeof(int), stream);
            scatter_kernel<<<(E + 255) / 256, 256, 0, stream>>>(
                srcA, dstA, eaA, offsets, cnt, meta, E, 0);
            qv_kernel<<<2048, 256, 0, stream>>>(xs, Wq, bq, Wv, bv, qv, Ns);
            if (rel == 0) {
                aggregate_chunks<<<(nC0 + 3) / 4, 256, 0, stream>>>(
                    P0, P1, qv, offsets, meta, nC0, nC0);
            } else {
                aggregate_chunks<<<(nC1 + 3) / 4, 256, 0, stream>>>(
                    P0, P1, qv, offsets, meta, 0, nC1);
            }
        }
    }

    count_kernel<<<1, 256, 0, stream>>>(batch_c, Nc, batch_b, Nb, cnt_c, cnt_b);

    mlp_kernel<<<NUM_G, H, 0, stream>>>(
        sum_c, sum_b, cnt_c, cnt_b,
        W1, b1, W2, b2, W3, b3, Wout, bout, (float*)d_out);
}

// Round 5
// 734.765 us; speedup vs baseline: 2.4582x; 1.2711x over previous
//
#include <hip/hip_runtime.h>
#include <math.h>

#define H 64
#define F 16
#define NUM_G 128
#define DPW 8   // dsts per wave chunk

__device__ __forceinline__ int lower_bound_i(const int* a, int n, int key) {
    int lo = 0, hi = n;
    while (lo < hi) { int mid = (lo + hi) >> 1; if (a[mid] < key) lo = mid + 1; else hi = mid; }
    return lo;
}

__device__ __forceinline__ unsigned bf16rne(float f) {
    unsigned u = __float_as_uint(f);
    return (u + 0x7fffu + ((u >> 16) & 1u)) >> 16;
}

__device__ __forceinline__ unsigned sel8u(unsigned a0, unsigned a1, unsigned a2, unsigned a3,
                                          unsigned a4, unsigned a5, unsigned a6, unsigned a7, int i) {
    unsigned b0 = (i & 1) ? a1 : a0, b1 = (i & 1) ? a3 : a2;
    unsigned b2 = (i & 1) ? a5 : a4, b3 = (i & 1) ? a7 : a6;
    unsigned c0 = (i & 2) ? b1 : b0, c1 = (i & 2) ? b3 : b2;
    return (i & 4) ? c1 : c0;
}
__device__ __forceinline__ int sel8i(int a0, int a1, int a2, int a3,
                                     int a4, int a5, int a6, int a7, int i) {
    int b0 = (i & 1) ? a1 : a0, b1 = (i & 1) ? a3 : a2;
    int b2 = (i & 1) ? a5 : a4, b3 = (i & 1) ? a7 : a6;
    int c0 = (i & 2) ? b1 : b0, c1 = (i & 2) ? b3 : b2;
    return (i & 4) ? c1 : c0;
}

// ---------------- CSR build ----------------

__global__ __launch_bounds__(256) void hist2_kernel(const int* __restrict__ dst0, int E0,
                                                    const int* __restrict__ dst1, int E1n,
                                                    int dstOff1, int* __restrict__ cnt) {
    int i = blockIdx.x * blockDim.x + threadIdx.x;
    if (i < E0) {
        atomicAdd(&cnt[dst0[i]], 1);
    } else {
        i -= E0;
        if (i < E1n) atomicAdd(&cnt[dstOff1 + dst1[i]], 1);
    }
}

__global__ __launch_bounds__(256) void scan_partial(const int* __restrict__ cnt,
                                                    int* __restrict__ bsums, int n) {
    __shared__ int red[256];
    const int b = blockIdx.x, t = threadIdx.x;
    const int base = b * 2048 + t * 8;
    int s = 0;
#pragma unroll
    for (int i = 0; i < 8; ++i) { int idx = base + i; if (idx < n) s += cnt[idx]; }
    red[t] = s;
    __syncthreads();
    for (int off = 128; off > 0; off >>= 1) {
        if (t < off) red[t] += red[t + off];
        __syncthreads();
    }
    if (t == 0) bsums[b] = red[0];
}

__global__ __launch_bounds__(256) void scan_bsums(int* __restrict__ bsums, int nb) {
    __shared__ int sh[256];
    const int t = threadIdx.x;
    sh[t] = (t < nb) ? bsums[t] : 0;
    __syncthreads();
    for (int off = 1; off < 256; off <<= 1) {
        int v = sh[t];
        int add = (t >= off) ? sh[t - off] : 0;
        __syncthreads();
        sh[t] = v + add;
        __syncthreads();
    }
    if (t < nb) bsums[t] = (t == 0) ? 0 : sh[t - 1];
}

__global__ __launch_bounds__(256) void scan_final(const int* __restrict__ cnt,
                                                  const int* __restrict__ bsums,
                                                  int* __restrict__ offsets, int n) {
    __shared__ int red[256];
    const int b = blockIdx.x, t = threadIdx.x;
    const int base = b * 2048 + t * 8;
    int v[8]; int s = 0;
#pragma unroll
    for (int i = 0; i < 8; ++i) { int idx = base + i; v[i] = (idx < n) ? cnt[idx] : 0; s += v[i]; }
    red[t] = s;
    __syncthreads();
    for (int off = 1; off < 256; off <<= 1) {
        int val = red[t];
        int add = (t >= off) ? red[t - off] : 0;
        __syncthreads();
        red[t] = val + add;
        __syncthreads();
    }
    const int ex = (t == 0) ? 0 : red[t - 1];
    int run = bsums[b] + ex;
#pragma unroll
    for (int i = 0; i < 8; ++i) {
        int idx = base + i;
        if (idx < n) offsets[idx] = run;
        run += v[i];
    }
    if (t == 255 && b == gridDim.x - 1) offsets[n] = run;
}

__global__ __launch_bounds__(256) void scatter2_kernel(
    const int* __restrict__ src0, const int* __restrict__ dst0,
    const float* __restrict__ ea0, int E0,
    const int* __restrict__ src1, const int* __restrict__ dst1,
    const float* __restrict__ ea1, int E1n,
    int dstOff1, int srcOff1,
    const int* __restrict__ offsets, int* __restrict__ cursor,
    int2* __restrict__ meta) {
    int i = blockIdx.x * blockDim.x + threadIdx.x;
    if (i < E0) {
        int d = dst0[i];
        int p = offsets[d] + atomicAdd(&cursor[d], 1);
        meta[p] = make_int2(src0[i], __float_as_int(ea0[i]));
    } else {
        i -= E0;
        if (i < E1n) {
            int d = dstOff1 + dst1[i];
            int p = offsets[d] + atomicAdd(&cursor[d], 1);
            meta[p] = make_int2(src1[i] + srcOff1, __float_as_int(ea1[i]));
        }
    }
}

// ---------------- per-node dual projection, packed bf16 ----------------
// outp[n*64+lane] = bf16(a) | bf16(b)<<16   (a = x@Wa+ba, b = x@Wb+bb)
__global__ __launch_bounds__(256) void proj2_kernel(
    const float* __restrict__ x,
    const float* __restrict__ Wa, const float* __restrict__ ba,
    const float* __restrict__ Wb, const float* __restrict__ bb,
    unsigned* __restrict__ outp, int N)
{
    const int lane = threadIdx.x & 63;
    float wa[F], wb[F];
#pragma unroll
    for (int f = 0; f < F; ++f) {
        wa[f] = Wa[f * H + lane];
        wb[f] = Wb[f * H + lane];
    }
    const float bah = ba[lane], bbh = bb[lane];
    const int wave = (blockIdx.x * (blockDim.x >> 6)) + (threadIdx.x >> 6);
    const int nw = gridDim.x * (blockDim.x >> 6);
    for (int n = wave; n < N; n += nw) {
        const float4* xr = (const float4*)(x + (size_t)n * F);
        float a = bah, b = bbh;
#pragma unroll
        for (int f4 = 0; f4 < F / 4; ++f4) {
            float4 t = xr[f4];
            a = fmaf(t.x, wa[4*f4+0], a); a = fmaf(t.y, wa[4*f4+1], a);
            a = fmaf(t.z, wa[4*f4+2], a); a = fmaf(t.w, wa[4*f4+3], a);
            b = fmaf(t.x, wb[4*f4+0], b); b = fmaf(t.y, wb[4*f4+1], b);
            b = fmaf(t.z, wb[4*f4+2], b); b = fmaf(t.w, wb[4*f4+3], b);
        }
        outp[(size_t)n * H + lane] = bf16rne(a) | (bf16rne(b) << 16);
    }
}

// ---------------- streaming aggregate (all deps prefetched) ----------------
struct RelP {
    const float* We; const float* be;
    const int* batch;
    float* psum;
    int Ndst;
    int offBase;   // offset into shared `offsets`
    int kskBase;   // row offset into kskp
};

__global__ __launch_bounds__(256) void aggregate_v2(
    RelP P0, RelP P1, const unsigned* __restrict__ qvp,
    const unsigned* __restrict__ kskp,
    const int* __restrict__ offsets, const int2* __restrict__ meta,
    int nChunk0, int chunkHi)
{
    const int lane = threadIdx.x & 63;
    const int cid = blockIdx.x * (blockDim.x >> 6) + (threadIdx.x >> 6);
    if (cid >= chunkHi) return;
    const bool r1 = (cid >= nChunk0);
    const RelP P = r1 ? P1 : P0;
    const int dLo = (r1 ? cid - nChunk0 : cid) * DPW;
    if (dLo >= P.Ndst) return;
    const int ndst = (P.Ndst - dLo < DPW) ? (P.Ndst - dLo) : DPW;

    const float weh = P.We[lane], beh = P.be[lane];

    // all chunk offsets upfront (clamped), one round trip
    const int* ob = offsets + P.offBase + dLo;
    int of0, of1, of2, of3, of4, of5, of6, of7, of8;
#define LDO(I) __builtin_amdgcn_readfirstlane(ob[(I) < ndst ? (I) : ndst])
    of0 = LDO(0); of1 = LDO(1); of2 = LDO(2); of3 = LDO(3); of4 = LDO(4);
    of5 = LDO(5); of6 = LDO(6); of7 = LDO(7); of8 = LDO(8);
#undef LDO

    // all chunk (k,sk) rows upfront, one round trip
    const unsigned* kb = kskp + (size_t)(P.kskBase + dLo) * H + lane;
    unsigned kp0 = 0, kp1 = 0, kp2 = 0, kp3 = 0, kp4 = 0, kp5 = 0, kp6 = 0, kp7 = 0;
    kp0 = kb[0];
    if (ndst > 1) kp1 = kb[1 * H];
    if (ndst > 2) kp2 = kb[2 * H];
    if (ndst > 3) kp3 = kb[3 * H];
    if (ndst > 4) kp4 = kb[4 * H];
    if (ndst > 5) kp5 = kb[5 * H];
    if (ndst > 6) kp6 = kb[6 * H];
    if (ndst > 7) kp7 = kb[7 * H];

    int idx = 0;
    float kcur = __uint_as_float(kp0 << 16);
    float skcur = __uint_as_float(kp0 & 0xffff0000u);
    int p = of0, pend = of1;
    const int pstop = of8;
    float acc = 0.f;

#define BATCH(NB, GUARDED)                                                     \
    {                                                                          \
        int2 m[16]; unsigned r[16];                                            \
        _Pragma("unroll")                                                      \
        for (int j = 0; j < 16; ++j)                                           \
            if (!(GUARDED) || j < (NB)) m[j] = meta[p + j];                    \
        _Pragma("unroll")                                                      \
        for (int j = 0; j < 16; ++j)                                           \
            if (!(GUARDED) || j < (NB)) r[j] = qvp[(size_t)m[j].x * H + lane]; \
        _Pragma("unroll")                                                      \
        for (int j = 0; j < 16; ++j) {                                         \
            if (!(GUARDED) || j < (NB)) {                                      \
                while (p + j >= pend) {                                        \
                    float hv = fmaxf(acc + skcur, 0.f);                        \
                    int gb = P.batch[dLo + idx];                               \
                    atomicAdd(&P.psum[(size_t)gb * H + lane], hv);             \
                    ++idx;                                                     \
                    unsigned kv = sel8u(kp0,kp1,kp2,kp3,kp4,kp5,kp6,kp7, idx); \
                    kcur = __uint_as_float(kv << 16);                          \
                    skcur = __uint_as_float(kv & 0xffff0000u);                 \
                    pend = sel8i(of1,of2,of3,of4,of5,of6,of7,of8, idx);        \
                    acc = 0.f;                                                 \
                }                                                              \
                float e = fmaf(__int_as_float(m[j].y), weh, beh);              \
                float qq = __uint_as_float(r[j] << 16);                        \
                float vv = __uint_as_float(r[j] & 0xffff0000u);                \
                float g = kcur + qq + 2.0f * e;                                \
                float sg = __fdividef(1.0f, 1.0f + __expf(-g));                \
                acc = fmaf(sg, vv + e, acc);                                   \
            }                                                                  \
        }                                                                      \
        p += (NB);                                                             \
    }

    while (p + 16 <= pstop) BATCH(16, false)
    if (p < pstop) { const int nb = pstop - p; BATCH(nb, true) }
#undef BATCH

    // flush current dst, then trailing (possibly empty) dsts
    for (;;) {
        float hv = fmaxf(acc + skcur, 0.f);
        int gb = P.batch[dLo + idx];
        atomicAdd(&P.psum[(size_t)gb * H + lane], hv);
        ++idx;
        if (idx >= ndst) break;
        unsigned kv = sel8u(kp0, kp1, kp2, kp3, kp4, kp5, kp6, kp7, idx);
        kcur = __uint_as_float(kv << 16);
        skcur = __uint_as_float(kv & 0xffff0000u);
        acc = 0.f;
    }
}

// ---------------- pooling counts + MLP ----------------
__global__ void count_kernel(const int* __restrict__ batch_c, int Nc,
                             const int* __restrict__ batch_b, int Nb,
                             float* __restrict__ cnt_c, float* __restrict__ cnt_b)
{
    int t = threadIdx.x;
    if (t < NUM_G) {
        int lo = lower_bound_i(batch_c, Nc, t);
        int hi = lower_bound_i(batch_c, Nc, t + 1);
        cnt_c[t] = (float)(hi - lo);
    } else if (t < 2 * NUM_G) {
        int g = t - NUM_G;
        int lo = lower_bound_i(batch_b, Nb, g);
        int hi = lower_bound_i(batch_b, Nb, g + 1);
        cnt_b[g] = (float)(hi - lo);
    }
}

__global__ __launch_bounds__(64) void mlp_kernel(
    const float* __restrict__ sum_c, const float* __restrict__ sum_b,
    const float* __restrict__ cnt_c, const float* __restrict__ cnt_b,
    const float* __restrict__ W1, const float* __restrict__ b1,
    const float* __restrict__ W2, const float* __restrict__ b2,
    const float* __restrict__ W3, const float* __restrict__ b3,
    const float* __restrict__ Wout, const float* __restrict__ bout,
    float* __restrict__ out)
{
    const int g = blockIdx.x;
    const int h = threadIdx.x;
    __shared__ float pld[2 * H];
    __shared__ float hbuf[H];
    const float cc = fmaxf(cnt_c[g], 1.f);
    const float cb = fmaxf(cnt_b[g], 1.f);
    pld[h] = sum_c[g * H + h] / cc;
    pld[H + h] = sum_b[g * H + h] / cb;
    __syncthreads();
    float a1 = b1[h];
    for (int j = 0; j < 2 * H; ++j) a1 = fmaf(pld[j], W1[j * H + h], a1);
    a1 = fmaxf(a1, 0.f);
    __syncthreads();
    hbuf[h] = a1;
    __syncthreads();
    float a2 = b2[h];
    for (int j = 0; j < H; ++j) a2 = fmaf(hbuf[j], W2[j * H + h], a2);
    a2 = fmaxf(a2, 0.f);
    __syncthreads();
    hbuf[h] = a2;
    __syncthreads();
    float a3 = b3[h];
    for (int j = 0; j < H; ++j) a3 = fmaf(hbuf[j], W3[j * H + h], a3);
    a3 = fmaxf(a3, 0.f);
    float p = a3 * Wout[h];
#pragma unroll
    for (int off = 32; off > 0; off >>= 1) p += __shfl_down(p, off, 64);
    if (h == 0) out[g] = p + bout[0];
}

extern "C" void kernel_launch(void* const* d_in, const int* in_sizes, int n_in,
                              void* d_out, int out_size, void* d_ws, size_t ws_size,
                              hipStream_t stream) {
    const float* x_x   = (const float*)d_in[0];
    const float* x_c   = (const float*)d_in[1];
    const float* x_b   = (const float*)d_in[2];
    const float* ea_ac = (const float*)d_in[3];
    const float* ea_cb = (const float*)d_in[4];

    const float* Wk_ac = (const float*)d_in[5];
    const float* Wq_ac = (const float*)d_in[6];
    const float* Wv_ac = (const float*)d_in[7];
    const float* Wskip_ac = (const float*)d_in[8];
    const float* We_ac = (const float*)d_in[9];
    const float* bk_ac = (const float*)d_in[10];
    const float* bq_ac = (const float*)d_in[11];
    const float* bv_ac = (const float*)d_in[12];
    const float* be_ac = (const float*)d_in[13];
    const float* bconv_ac = (const float*)d_in[14];

    const float* Wk_cb = (const float*)d_in[15];
    const float* Wq_cb = (const float*)d_in[16];
    const float* Wv_cb = (const float*)d_in[17];
    const float* Wskip_cb = (const float*)d_in[18];
    const float* We_cb = (const float*)d_in[19];
    const float* bk_cb = (const float*)d_in[20];
    const float* bq_cb = (const float*)d_in[21];
    const float* bv_cb = (const float*)d_in[22];
    const float* be_cb = (const float*)d_in[23];
    const float* bconv_cb = (const float*)d_in[24];

    const float* W1 = (const float*)d_in[25];
    const float* b1 = (const float*)d_in[26];
    const float* W2 = (const float*)d_in[27];
    const float* b2 = (const float*)d_in[28];
    const float* W3 = (const float*)d_in[29];
    const float* b3 = (const float*)d_in[30];
    const float* Wout = (const float*)d_in[31];
    const float* bout = (const float*)d_in[32];

    const int* src_ac = (const int*)d_in[33];
    const int* dst_ac = (const int*)d_in[34];
    const int* src_cb = (const int*)d_in[35];
    const int* dst_cb = (const int*)d_in[36];
    const int* batch_c = (const int*)d_in[37];
    const int* batch_b = (const int*)d_in[38];

    const int Nx = in_sizes[0] / F;
    const int Nc = in_sizes[1] / F;
    const int Nb = in_sizes[2] / F;
    const int E1 = in_sizes[33];
    const int E2 = in_sizes[35];
    (void)n_in; (void)out_size;

    const int NT = Nc + Nb;
    const size_t ET = (size_t)E1 + E2;
    const int NMAX = (Nc > Nb ? Nc : Nb);
    const int EMAX = (E1 > E2 ? E1 : E2);
    const int SRCMAX = (Nx > Nc ? Nx : Nc);
    const size_t SUMS = 2 * NUM_G * H + 2 * NUM_G;

    // path A (fused): [meta 2*ET][offsets NT+1][cnt NT][bsums 256][sums][qvp (Nx+Nc)*64][kskp (Nc+Nb)*64]
    const size_t wordsA = 2 * ET + (size_t)(NT + 1) + NT + 256 + SUMS
                        + (size_t)(Nx + Nc) * H + (size_t)(Nc + Nb) * H;
    const bool pathA = (ws_size >= wordsA * 4);

    int* ws = (int*)d_ws;
    const size_t metaN = pathA ? 2 * ET : 2 * (size_t)EMAX;
    const int nOff = pathA ? NT : NMAX;
    int2*     meta    = (int2*)ws;
    int*      offsets = ws + metaN;
    int*      cnt     = offsets + (nOff + 1);
    int*      bsums   = cnt + nOff;
    float*    sum_c   = (float*)(bsums + 256);
    float*    sum_b   = sum_c + NUM_G * H;
    float*    cnt_c   = sum_b + NUM_G * H;
    float*    cnt_b   = cnt_c + NUM_G;
    unsigned* qvp     = (unsigned*)(cnt_b + NUM_G);
    unsigned* kskp    = qvp + (size_t)(pathA ? (Nx + Nc) : SRCMAX) * H;

    hipMemsetAsync(sum_c, 0, SUMS * sizeof(float), stream);

    const int nC0 = (Nc + DPW - 1) / DPW;
    const int nC1 = (Nb + DPW - 1) / DPW;

    RelP P0, P1;
    P0.We = We_ac; P0.be = be_ac; P0.batch = batch_c; P0.psum = sum_c;
    P0.Ndst = Nc; P0.offBase = 0; P0.kskBase = 0;
    P1.We = We_cb; P1.be = be_cb; P1.batch = batch_b; P1.psum = sum_b;
    P1.Ndst = Nb; P1.offBase = pathA ? Nc : 0; P1.kskBase = pathA ? Nc : 0;

    if (pathA) {
        const int nScan = (NT + 2047) / 2048;
        const int EB = (int)((ET + 255) / 256);
        hipMemsetAsync(cnt, 0, NT * sizeof(int), stream);
        hist2_kernel<<<EB, 256, 0, stream>>>(dst_ac, E1, dst_cb, E2, Nc, cnt);
        scan_partial<<<nScan, 256, 0, stream>>>(cnt, bsums, NT);
        scan_bsums<<<1, 256, 0, stream>>>(bsums, nScan);
        scan_final<<<nScan, 256, 0, stream>>>(cnt, bsums, offsets, NT);
        hipMemsetAsync(cnt, 0, NT * sizeof(int), stream);
        scatter2_kernel<<<EB, 256, 0, stream>>>(
            src_ac, dst_ac, ea_ac, E1, src_cb, dst_cb, ea_cb, E2,
            Nc, Nx, offsets, cnt, meta);
        // projections: qvp rows [0,Nx)=x_x(q,v ac), [Nx,Nx+Nc)=x_c(q,v cb)
        //              kskp rows [0,Nc)=x_c(k,sk ac), [Nc,Nc+Nb)=x_b(k,sk cb)
        proj2_kernel<<<1024, 256, 0, stream>>>(x_x, Wq_ac, bq_ac, Wv_ac, bv_ac, qvp, Nx);
        proj2_kernel<<<1024, 256, 0, stream>>>(x_c, Wq_cb, bq_cb, Wv_cb, bv_cb,
                                               qvp + (size_t)Nx * H, Nc);
        proj2_kernel<<<1024, 256, 0, stream>>>(x_c, Wk_ac, bk_ac, Wskip_ac, bconv_ac, kskp, Nc);
        proj2_kernel<<<1024, 256, 0, stream>>>(x_b, Wk_cb, bk_cb, Wskip_cb, bconv_cb,
                                               kskp + (size_t)Nc * H, Nb);
        const int nW = nC0 + nC1;
        aggregate_v2<<<(nW + 3) / 4, 256, 0, stream>>>(
            P0, P1, qvp, kskp, offsets, meta, nC0, nW);
    } else {
        for (int rel = 0; rel < 2; ++rel) {
            const int n = rel ? Nb : Nc;
            const int E = rel ? E2 : E1;
            const int Ns = rel ? Nc : Nx;
            const int* srcA = rel ? src_cb : src_ac;
            const int* dstA = rel ? dst_cb : dst_ac;
            const float* eaA = rel ? ea_cb : ea_ac;
            const float* xs = rel ? x_c : x_x;
            const float* xd = rel ? x_b : x_c;
            const float* Wq = rel ? Wq_cb : Wq_ac; const float* bq = rel ? bq_cb : bq_ac;
            const float* Wv = rel ? Wv_cb : Wv_ac; const float* bv = rel ? bv_cb : bv_ac;
            const float* Wk = rel ? Wk_cb : Wk_ac; const float* bk = rel ? bk_cb : bk_ac;
            const float* Wsk = rel ? Wskip_cb : Wskip_ac;
            const float* bcv = rel ? bconv_cb : bconv_ac;
            const int nScan = (n + 2047) / 2048;
            hipMemsetAsync(cnt, 0, n * sizeof(int), stream);
            hist2_kernel<<<(E + 255) / 256, 256, 0, stream>>>(dstA, E, dstA, 0, 0, cnt);
            scan_partial<<<nScan, 256, 0, stream>>>(cnt, bsums, n);
            scan_bsums<<<1, 256, 0, stream>>>(bsums, nScan);
            scan_final<<<nScan, 256, 0, stream>>>(cnt, bsums, offsets, n);
            hipMemsetAsync(cnt, 0, n * sizeof(int), stream);
            scatter2_kernel<<<(E + 255) / 256, 256, 0, stream>>>(
                srcA, dstA, eaA, E, srcA, dstA, eaA, 0, 0, 0, offsets, cnt, meta);
            proj2_kernel<<<1024, 256, 0, stream>>>(xs, Wq, bq, Wv, bv, qvp, Ns);
            proj2_kernel<<<1024, 256, 0, stream>>>(xd, Wk, bk, Wsk, bcv, kskp, n);
            RelP PR = rel ? P1 : P0;
            const int nCr = rel ? nC1 : nC0;
            aggregate_v2<<<(nCr + 3) / 4, 256, 0, stream>>>(
                PR, PR, qvp, kskp, offsets, meta, nCr, nCr);
        }
    }

    count_kernel<<<1, 256, 0, stream>>>(batch_c, Nc, batch_b, Nb, cnt_c, cnt_b);

    mlp_kernel<<<NUM_G, H, 0, stream>>>(
        sum_c, sum_b, cnt_c, cnt_b,
        W1, b1, W2, b2, W3, b3, Wout, bout, (float*)d_out);
}

// Round 6
// 725.800 us; speedup vs baseline: 2.4886x; 1.0124x over previous
//
#include <hip/hip_runtime.h>
#include <math.h>

#define H 64
#define F 16
#define NUM_G 128
#define DPW 8   // dsts per wave chunk
#define L2E 1.4426950408889634f
#define TWO_L2E 2.8853900817779268f

__device__ __forceinline__ int lower_bound_i(const int* a, int n, int key) {
    int lo = 0, hi = n;
    while (lo < hi) { int mid = (lo + hi) >> 1; if (a[mid] < key) lo = mid + 1; else hi = mid; }
    return lo;
}

__device__ __forceinline__ unsigned bf16rne(float f) {
    unsigned u = __float_as_uint(f);
    return (u + 0x7fffu + ((u >> 16) & 1u)) >> 16;
}

__device__ __forceinline__ unsigned sel8u(unsigned a0, unsigned a1, unsigned a2, unsigned a3,
                                          unsigned a4, unsigned a5, unsigned a6, unsigned a7, int i) {
    unsigned b0 = (i & 1) ? a1 : a0, b1 = (i & 1) ? a3 : a2;
    unsigned b2 = (i & 1) ? a5 : a4, b3 = (i & 1) ? a7 : a6;
    unsigned c0 = (i & 2) ? b1 : b0, c1 = (i & 2) ? b3 : b2;
    return (i & 4) ? c1 : c0;
}
__device__ __forceinline__ int sel8i(int a0, int a1, int a2, int a3,
                                     int a4, int a5, int a6, int a7, int i) {
    int b0 = (i & 1) ? a1 : a0, b1 = (i & 1) ? a3 : a2;
    int b2 = (i & 1) ? a5 : a4, b3 = (i & 1) ? a7 : a6;
    int c0 = (i & 2) ? b1 : b0, c1 = (i & 2) ? b3 : b2;
    return (i & 4) ? c1 : c0;
}

// ---------------- CSR build ----------------

__global__ __launch_bounds__(256) void hist2_kernel(const int* __restrict__ dst0, int E0,
                                                    const int* __restrict__ dst1, int E1n,
                                                    int dstOff1, int* __restrict__ cnt) {
    int i = blockIdx.x * blockDim.x + threadIdx.x;
    if (i < E0) {
        atomicAdd(&cnt[dst0[i]], 1);
    } else {
        i -= E0;
        if (i < E1n) atomicAdd(&cnt[dstOff1 + dst1[i]], 1);
    }
}

__global__ __launch_bounds__(256) void scan_partial(const int* __restrict__ cnt,
                                                    int* __restrict__ bsums, int n) {
    __shared__ int red[256];
    const int b = blockIdx.x, t = threadIdx.x;
    const int base = b * 2048 + t * 8;
    int s = 0;
#pragma unroll
    for (int i = 0; i < 8; ++i) { int idx = base + i; if (idx < n) s += cnt[idx]; }
    red[t] = s;
    __syncthreads();
    for (int off = 128; off > 0; off >>= 1) {
        if (t < off) red[t] += red[t + off];
        __syncthreads();
    }
    if (t == 0) bsums[b] = red[0];
}

__global__ __launch_bounds__(256) void scan_bsums(int* __restrict__ bsums, int nb) {
    __shared__ int sh[256];
    const int t = threadIdx.x;
    sh[t] = (t < nb) ? bsums[t] : 0;
    __syncthreads();
    for (int off = 1; off < 256; off <<= 1) {
        int v = sh[t];
        int add = (t >= off) ? sh[t - off] : 0;
        __syncthreads();
        sh[t] = v + add;
        __syncthreads();
    }
    if (t < nb) bsums[t] = (t == 0) ? 0 : sh[t - 1];
}

// writes offsets[idx]=prefix AND cnt[idx]=prefix (cursor init, in place)
__global__ __launch_bounds__(256) void scan_final(int* __restrict__ cnt,
                                                  const int* __restrict__ bsums,
                                                  int* __restrict__ offsets, int n) {
    __shared__ int red[256];
    const int b = blockIdx.x, t = threadIdx.x;
    const int base = b * 2048 + t * 8;
    int v[8]; int s = 0;
#pragma unroll
    for (int i = 0; i < 8; ++i) { int idx = base + i; v[i] = (idx < n) ? cnt[idx] : 0; s += v[i]; }
    red[t] = s;
    __syncthreads();
    for (int off = 1; off < 256; off <<= 1) {
        int val = red[t];
        int add = (t >= off) ? red[t - off] : 0;
        __syncthreads();
        red[t] = val + add;
        __syncthreads();
    }
    const int ex = (t == 0) ? 0 : red[t - 1];
    int run = bsums[b] + ex;
#pragma unroll
    for (int i = 0; i < 8; ++i) {
        int idx = base + i;
        if (idx < n) { offsets[idx] = run; cnt[idx] = run; }
        run += v[i];
    }
    if (t == 255 && b == gridDim.x - 1) offsets[n] = run;
}

// cursor pre-initialized to offsets; atomicAdd returns absolute slot
__global__ __launch_bounds__(256) void scatter2_kernel(
    const int* __restrict__ src0, const int* __restrict__ dst0,
    const float* __restrict__ ea0, int E0,
    const int* __restrict__ src1, const int* __restrict__ dst1,
    const float* __restrict__ ea1, int E1n,
    int dstOff1, int srcOff1,
    int* __restrict__ cursor, int2* __restrict__ meta) {
    int i = blockIdx.x * blockDim.x + threadIdx.x;
    if (i < E0) {
        int d = dst0[i];
        int p = atomicAdd(&cursor[d], 1);
        meta[p] = make_int2(src0[i], __float_as_int(ea0[i]));
    } else {
        i -= E0;
        if (i < E1n) {
            int d = dstOff1 + dst1[i];
            int p = atomicAdd(&cursor[d], 1);
            meta[p] = make_int2(src1[i] + srcOff1, __float_as_int(ea1[i]));
        }
    }
}

// ---------------- fused projections, packed bf16 (a-half scaled by scaleA) ----------------
struct ProjSec {
    const float* x; const float* Wa; const float* ba;
    const float* Wb; const float* bb2; unsigned* out;
    int N; int waveOff; float scaleA;
};

#define PROJ_ROWS 16

__global__ __launch_bounds__(256) void proj_all_kernel(
    ProjSec s0, ProjSec s1, ProjSec s2, ProjSec s3, int wTot)
{
    const int lane = threadIdx.x & 63;
    const int w = blockIdx.x * (blockDim.x >> 6) + (threadIdx.x >> 6);
    if (w >= wTot) return;
    ProjSec S = (w >= s3.waveOff) ? s3 : (w >= s2.waveOff) ? s2 : (w >= s1.waveOff) ? s1 : s0;
    const int r0 = (w - S.waveOff) * PROJ_ROWS;
    float wa[F], wb[F];
#pragma unroll
    for (int f = 0; f < F; ++f) {
        wa[f] = S.Wa[f * H + lane] * S.scaleA;
        wb[f] = S.Wb[f * H + lane];
    }
    const float bah = S.ba[lane] * S.scaleA, bbh = S.bb2[lane];
    int r1e = r0 + PROJ_ROWS; if (r1e > S.N) r1e = S.N;
    for (int n = r0; n < r1e; ++n) {
        const float4* xr = (const float4*)(S.x + (size_t)n * F);
        float a = bah, b = bbh;
#pragma unroll
        for (int f4 = 0; f4 < F / 4; ++f4) {
            float4 t = xr[f4];
            a = fmaf(t.x, wa[4*f4+0], a); a = fmaf(t.y, wa[4*f4+1], a);
            a = fmaf(t.z, wa[4*f4+2], a); a = fmaf(t.w, wa[4*f4+3], a);
            b = fmaf(t.x, wb[4*f4+0], b); b = fmaf(t.y, wb[4*f4+1], b);
            b = fmaf(t.z, wb[4*f4+2], b); b = fmaf(t.w, wb[4*f4+3], b);
        }
        S.out[(size_t)n * H + lane] = bf16rne(a) | (bf16rne(b) << 16);
    }
}

// ---------------- double-buffered streaming aggregate ----------------
struct RelP {
    const float* We; const float* be;
    const int* batch;
    float* psum;
    int Ndst;
    int offBase;   // into shared offsets
    int kskBase;   // row offset into kskp
};

__global__ __launch_bounds__(256) void aggregate_v3(
    RelP P0, RelP P1, const unsigned* __restrict__ qvp,
    const unsigned* __restrict__ kskp,
    const int* __restrict__ offsets, const int2* __restrict__ meta,
    int nChunk0, int chunkHi)
{
    const int lane = threadIdx.x & 63;
    const int cid = blockIdx.x * (blockDim.x >> 6) + (threadIdx.x >> 6);
    if (cid >= chunkHi) return;
    const bool r1 = (cid >= nChunk0);
    const RelP P = r1 ? P1 : P0;
    const int dLo = (r1 ? cid - nChunk0 : cid) * DPW;
    if (dLo >= P.Ndst) return;
    const int ndst = (P.Ndst - dLo < DPW) ? (P.Ndst - dLo) : DPW;

    const float weh = P.We[lane], beh = P.be[lane];

    // chunk CSR bounds + graph ids, scalar
    const int* ob = offsets + P.offBase + dLo;
    const int* bb_ = P.batch + dLo;
    int of0, of1, of2, of3, of4, of5, of6, of7, of8;
    int bg0, bg1, bg2, bg3, bg4, bg5, bg6, bg7;
#define LDO(I) __builtin_amdgcn_readfirstlane(ob[(I) < ndst ? (I) : ndst])
#define LDB(I) __builtin_amdgcn_readfirstlane(bb_[(I) < ndst ? (I) : (ndst - 1)])
    of0 = LDO(0); of1 = LDO(1); of2 = LDO(2); of3 = LDO(3); of4 = LDO(4);
    of5 = LDO(5); of6 = LDO(6); of7 = LDO(7); of8 = LDO(8);
    bg0 = LDB(0); bg1 = LDB(1); bg2 = LDB(2); bg3 = LDB(3);
    bg4 = LDB(4); bg5 = LDB(5); bg6 = LDB(6); bg7 = LDB(7);
#undef LDO
#undef LDB

    // packed (k', sk) rows, one round trip
    const unsigned* kb = kskp + (size_t)(P.kskBase + dLo) * H + lane;
    unsigned kp0 = kb[0], kp1 = 0, kp2 = 0, kp3 = 0, kp4 = 0, kp5 = 0, kp6 = 0, kp7 = 0;
    if (ndst > 1) kp1 = kb[1 * H];
    if (ndst > 2) kp2 = kb[2 * H];
    if (ndst > 3) kp3 = kb[3 * H];
    if (ndst > 4) kp4 = kb[4 * H];
    if (ndst > 5) kp5 = kb[5 * H];
    if (ndst > 6) kp6 = kb[6 * H];
    if (ndst > 7) kp7 = kb[7 * H];

    const unsigned* qvl = qvp + lane;

    int idx = 0;
    float kcur = __uint_as_float(kp0 << 16);          // k' (log2e-scaled) bf16
    float skcur = __uint_as_float(kp0 & 0xffff0000u); // skip+bias f32-from-bf16
    int pend = of1;
    int bgcur = bg0;
    float acc = 0.f;
    const int base = of0;
    const int pstop = of8;
    const int nbatch = (pstop - base + 7) >> 3;

#define ADVANCE()                                                              \
    {                                                                          \
        float hv = fmaxf(acc + skcur, 0.f);                                    \
        atomicAdd(&P.psum[(size_t)bgcur * H + lane], hv);                      \
        ++idx;                                                                 \
        unsigned kv = sel8u(kp0, kp1, kp2, kp3, kp4, kp5, kp6, kp7, idx);      \
        kcur = __uint_as_float(kv << 16);                                      \
        skcur = __uint_as_float(kv & 0xffff0000u);                             \
        pend = sel8i(of1, of2, of3, of4, of5, of6, of7, of8, idx);             \
        bgcur = sel8i(bg0, bg1, bg2, bg3, bg4, bg5, bg6, bg7, idx);            \
        acc = 0.f;                                                             \
    }

#define ISSUE(MB, RB, BI)                                                      \
    {                                                                          \
        const int s_ = base + (BI) * 8;                                        \
        _Pragma("unroll")                                                      \
        for (int j = 0; j < 8; ++j) {                                          \
            int pos = s_ + j; if (pos > pstop - 1) pos = pstop - 1;            \
            MB[j] = meta[pos];                                                 \
        }                                                                      \
        _Pragma("unroll")                                                      \
        for (int j = 0; j < 8; ++j)                                            \
            RB[j] = qvl[(size_t)((unsigned)MB[j].x * (unsigned)H)];            \
    }

#define CONSUME(MB, RB, BI)                                                    \
    {                                                                          \
        const int s_ = base + (BI) * 8;                                        \
        int n_ = pstop - s_; if (n_ > 8) n_ = 8;                               \
        _Pragma("unroll")                                                      \
        for (int j = 0; j < 8; ++j) {                                          \
            if (j < n_) {                                                      \
                while (s_ + j >= pend) ADVANCE();                              \
                float e = fmaf(__int_as_float(MB[j].y), weh, beh);             \
                float qq = __uint_as_float(RB[j] << 16);                       \
                float vv = __uint_as_float(RB[j] & 0xffff0000u);               \
                float g2 = fmaf(TWO_L2E, e, kcur + qq);                        \
                float sg = __builtin_amdgcn_rcpf(1.0f + __builtin_amdgcn_exp2f(-g2)); \
                acc = fmaf(sg, vv + e, acc);                                   \
            }                                                                  \
        }                                                                      \
    }

    if (nbatch > 0) {
        int2 mA[8], mB[8];
        unsigned rA[8], rB[8];
        ISSUE(mA, rA, 0);
        int i = 0;
        for (;;) {
            if (i + 1 < nbatch) ISSUE(mB, rB, i + 1);
            CONSUME(mA, rA, i);
            ++i; if (i >= nbatch) break;
            if (i + 1 < nbatch) ISSUE(mA, rA, i + 1);
            CONSUME(mB, rB, i);
            ++i; if (i >= nbatch) break;
        }
    }
#undef ISSUE
#undef CONSUME

    // flush current dst, then trailing (possibly empty) dsts
    for (;;) {
        float hv = fmaxf(acc + skcur, 0.f);
        atomicAdd(&P.psum[(size_t)bgcur * H + lane], hv);
        ++idx;
        if (idx >= ndst) break;
        unsigned kv = sel8u(kp0, kp1, kp2, kp3, kp4, kp5, kp6, kp7, idx);
        kcur = __uint_as_float(kv << 16);
        skcur = __uint_as_float(kv & 0xffff0000u);
        bgcur = sel8i(bg0, bg1, bg2, bg3, bg4, bg5, bg6, bg7, idx);
        acc = 0.f;
    }
#undef ADVANCE
}

// ---------------- MLP with fused per-graph counts ----------------
__global__ __launch_bounds__(64) void mlp_kernel(
    const float* __restrict__ sum_c, const float* __restrict__ sum_b,
    const int* __restrict__ batch_c, int Nc,
    const int* __restrict__ batch_b, int Nb,
    const float* __restrict__ W1, const float* __restrict__ b1,
    const float* __restrict__ W2, const float* __restrict__ b2,
    const float* __restrict__ W3, const float* __restrict__ b3,
    const float* __restrict__ Wout, const float* __restrict__ bout,
    float* __restrict__ out)
{
    const int g = blockIdx.x;
    const int h = threadIdx.x;
    __shared__ float pld[2 * H];
    __shared__ float hbuf[H];
    __shared__ float cnts[2];
    if (h < 2) {
        const int* a = h ? batch_b : batch_c;
        const int n = h ? Nb : Nc;
        int lo = lower_bound_i(a, n, g);
        int hi = lower_bound_i(a, n, g + 1);
        cnts[h] = fmaxf((float)(hi - lo), 1.f);
    }
    __syncthreads();
    pld[h] = sum_c[g * H + h] / cnts[0];
    pld[H + h] = sum_b[g * H + h] / cnts[1];
    __syncthreads();
    float a1 = b1[h];
    for (int j = 0; j < 2 * H; ++j) a1 = fmaf(pld[j], W1[j * H + h], a1);
    a1 = fmaxf(a1, 0.f);
    __syncthreads();
    hbuf[h] = a1;
    __syncthreads();
    float a2 = b2[h];
    for (int j = 0; j < H; ++j) a2 = fmaf(hbuf[j], W2[j * H + h], a2);
    a2 = fmaxf(a2, 0.f);
    __syncthreads();
    hbuf[h] = a2;
    __syncthreads();
    float a3 = b3[h];
    for (int j = 0; j < H; ++j) a3 = fmaf(hbuf[j], W3[j * H + h], a3);
    a3 = fmaxf(a3, 0.f);
    float p = a3 * Wout[h];
#pragma unroll
    for (int off = 32; off > 0; off >>= 1) p += __shfl_down(p, off, 64);
    if (h == 0) out[g] = p + bout[0];
}

extern "C" void kernel_launch(void* const* d_in, const int* in_sizes, int n_in,
                              void* d_out, int out_size, void* d_ws, size_t ws_size,
                              hipStream_t stream) {
    const float* x_x   = (const float*)d_in[0];
    const float* x_c   = (const float*)d_in[1];
    const float* x_b   = (const float*)d_in[2];
    const float* ea_ac = (const float*)d_in[3];
    const float* ea_cb = (const float*)d_in[4];

    const float* Wk_ac = (const float*)d_in[5];
    const float* Wq_ac = (const float*)d_in[6];
    const float* Wv_ac = (const float*)d_in[7];
    const float* Wskip_ac = (const float*)d_in[8];
    const float* We_ac = (const float*)d_in[9];
    const float* bk_ac = (const float*)d_in[10];
    const float* bq_ac = (const float*)d_in[11];
    const float* bv_ac = (const float*)d_in[12];
    const float* be_ac = (const float*)d_in[13];
    const float* bconv_ac = (const float*)d_in[14];

    const float* Wk_cb = (const float*)d_in[15];
    const float* Wq_cb = (const float*)d_in[16];
    const float* Wv_cb = (const float*)d_in[17];
    const float* Wskip_cb = (const float*)d_in[18];
    const float* We_cb = (const float*)d_in[19];
    const float* bk_cb = (const float*)d_in[20];
    const float* bq_cb = (const float*)d_in[21];
    const float* bv_cb = (const float*)d_in[22];
    const float* be_cb = (const float*)d_in[23];
    const float* bconv_cb = (const float*)d_in[24];

    const float* W1 = (const float*)d_in[25];
    const float* b1 = (const float*)d_in[26];
    const float* W2 = (const float*)d_in[27];
    const float* b2 = (const float*)d_in[28];
    const float* W3 = (const float*)d_in[29];
    const float* b3 = (const float*)d_in[30];
    const float* Wout = (const float*)d_in[31];
    const float* bout = (const float*)d_in[32];

    const int* src_ac = (const int*)d_in[33];
    const int* dst_ac = (const int*)d_in[34];
    const int* src_cb = (const int*)d_in[35];
    const int* dst_cb = (const int*)d_in[36];
    const int* batch_c = (const int*)d_in[37];
    const int* batch_b = (const int*)d_in[38];

    const int Nx = in_sizes[0] / F;
    const int Nc = in_sizes[1] / F;
    const int Nb = in_sizes[2] / F;
    const int E1 = in_sizes[33];
    const int E2 = in_sizes[35];
    (void)n_in; (void)out_size;

    const int NT = Nc + Nb;
    const size_t ET = (size_t)E1 + E2;
    const int NMAX = (Nc > Nb ? Nc : Nb);
    const int EMAX = (E1 > E2 ? E1 : E2);
    const int SRCMAX = (Nx > Nc ? Nx : Nc);
    const size_t SUMS = 2 * NUM_G * H;

    const size_t wordsA = 2 * ET + (size_t)(NT + 1) + NT + 256 + SUMS
                        + (size_t)(Nx + Nc) * H + (size_t)(Nc + Nb) * H;
    const bool pathA = (ws_size >= wordsA * 4);

    int* ws = (int*)d_ws;
    const size_t metaN = pathA ? 2 * ET : 2 * (size_t)EMAX;
    const int nOff = pathA ? NT : NMAX;
    int2*     meta    = (int2*)ws;
    int*      offsets = ws + metaN;
    int*      cnt     = offsets + (nOff + 1);
    int*      bsums   = cnt + nOff;
    float*    sum_c   = (float*)(bsums + 256);
    float*    sum_b   = sum_c + NUM_G * H;
    unsigned* qvp     = (unsigned*)(sum_b + NUM_G * H);
    unsigned* kskp    = qvp + (size_t)(pathA ? (Nx + Nc) : SRCMAX) * H;

    hipMemsetAsync(sum_c, 0, SUMS * sizeof(float), stream);

    const int nC0 = (Nc + DPW - 1) / DPW;
    const int nC1 = (Nb + DPW - 1) / DPW;

    RelP P0, P1;
    P0.We = We_ac; P0.be = be_ac; P0.batch = batch_c; P0.psum = sum_c;
    P0.Ndst = Nc; P0.offBase = 0; P0.kskBase = 0;
    P1.We = We_cb; P1.be = be_cb; P1.batch = batch_b; P1.psum = sum_b;
    P1.Ndst = Nb; P1.offBase = pathA ? Nc : 0; P1.kskBase = pathA ? Nc : 0;

    if (pathA) {
        const int nScan = (NT + 2047) / 2048;
        const int EB = (int)((ET + 255) / 256);
        hipMemsetAsync(cnt, 0, NT * sizeof(int), stream);
        hist2_kernel<<<EB, 256, 0, stream>>>(dst_ac, E1, dst_cb, E2, Nc, cnt);
        scan_partial<<<nScan, 256, 0, stream>>>(cnt, bsums, NT);
        scan_bsums<<<1, 256, 0, stream>>>(bsums, nScan);
        scan_final<<<nScan, 256, 0, stream>>>(cnt, bsums, offsets, NT);
        scatter2_kernel<<<EB, 256, 0, stream>>>(
            src_ac, dst_ac, ea_ac, E1, src_cb, dst_cb, ea_cb, E2,
            Nc, Nx, cnt, meta);

        // projections: qvp rows [0,Nx)=x_x (q',v | ac), [Nx,Nx+Nc)=x_c (q',v | cb)
        //              kskp rows [0,Nc)=x_c (k',sk | ac), [Nc,Nc+Nb)=x_b (k',sk | cb)
        const int w1 = (Nx + PROJ_ROWS - 1) / PROJ_ROWS;
        const int w2 = w1 + (Nc + PROJ_ROWS - 1) / PROJ_ROWS;
        const int w3 = w2 + (Nc + PROJ_ROWS - 1) / PROJ_ROWS;
        const int wTot = w3 + (Nb + PROJ_ROWS - 1) / PROJ_ROWS;
        ProjSec s0 = { x_x, Wq_ac, bq_ac, Wv_ac, bv_ac, qvp, Nx, 0, L2E };
        ProjSec s1 = { x_c, Wq_cb, bq_cb, Wv_cb, bv_cb, qvp + (size_t)Nx * H, Nc, w1, L2E };
        ProjSec s2 = { x_c, Wk_ac, bk_ac, Wskip_ac, bconv_ac, kskp, Nc, w2, L2E };
        ProjSec s3 = { x_b, Wk_cb, bk_cb, Wskip_cb, bconv_cb, kskp + (size_t)Nc * H, Nb, w3, L2E };
        proj_all_kernel<<<(wTot + 3) / 4, 256, 0, stream>>>(s0, s1, s2, s3, wTot);

        const int nW = nC0 + nC1;
        aggregate_v3<<<(nW + 3) / 4, 256, 0, stream>>>(
            P0, P1, qvp, kskp, offsets, meta, nC0, nW);
    } else {
        for (int rel = 0; rel < 2; ++rel) {
            const int n = rel ? Nb : Nc;
            const int E = rel ? E2 : E1;
            const int Ns = rel ? Nc : Nx;
            const int* srcA = rel ? src_cb : src_ac;
            const int* dstA = rel ? dst_cb : dst_ac;
            const float* eaA = rel ? ea_cb : ea_ac;
            const float* xs = rel ? x_c : x_x;
            const float* xd = rel ? x_b : x_c;
            const float* Wq = rel ? Wq_cb : Wq_ac; const float* bq = rel ? bq_cb : bq_ac;
            const float* Wv = rel ? Wv_cb : Wv_ac; const float* bv = rel ? bv_cb : bv_ac;
            const float* Wk = rel ? Wk_cb : Wk_ac; const float* bk = rel ? bk_cb : bk_ac;
            const float* Wsk = rel ? Wskip_cb : Wskip_ac;
            const float* bcv = rel ? bconv_cb : bconv_ac;
            const int nScan = (n + 2047) / 2048;
            hipMemsetAsync(cnt, 0, n * sizeof(int), stream);
            hist2_kernel<<<(E + 255) / 256, 256, 0, stream>>>(dstA, E, dstA, 0, 0, cnt);
            scan_partial<<<nScan, 256, 0, stream>>>(cnt, bsums, n);
            scan_bsums<<<1, 256, 0, stream>>>(bsums, nScan);
            scan_final<<<nScan, 256, 0, stream>>>(cnt, bsums, offsets, n);
            scatter2_kernel<<<(E + 255) / 256, 256, 0, stream>>>(
                srcA, dstA, eaA, E, srcA, dstA, eaA, 0, 0, 0, cnt, meta);
            const int w1 = (Ns + PROJ_ROWS - 1) / PROJ_ROWS;
            const int wTot = w1 + (n + PROJ_ROWS - 1) / PROJ_ROWS;
            ProjSec s0 = { xs, Wq, bq, Wv, bv, qvp, Ns, 0, L2E };
            ProjSec s1 = { xs, Wq, bq, Wv, bv, qvp, 0, w1, L2E };
            ProjSec s2 = { xd, Wk, bk, Wsk, bcv, kskp, n, w1, L2E };
            ProjSec s3 = { xd, Wk, bk, Wsk, bcv, kskp, 0, wTot, L2E };
            proj_all_kernel<<<(wTot + 3) / 4, 256, 0, stream>>>(s0, s1, s2, s3, wTot);
            RelP PR = rel ? P1 : P0;
            const int nCr = rel ? nC1 : nC0;
            aggregate_v3<<<(nCr + 3) / 4, 256, 0, stream>>>(
                PR, PR, qvp, kskp, offsets, meta, nCr, nCr);
        }
    }

    mlp_kernel<<<NUM_G, 64, 0, stream>>>(
        sum_c, sum_b, batch_c, Nc, batch_b, Nb,
        W1, b1, W2, b2, W3, b3, Wout, bout, (float*)d_out);
}

// Round 7
// 709.614 us; speedup vs baseline: 2.5454x; 1.0228x over previous
//
#include <hip/hip_runtime.h>
#include <math.h>

#define H 64
#define F 16
#define NUM_G 128
#define DPW 8   // dsts per wave chunk
#define L2E 1.4426950408889634f
#define TWO_L2E 2.8853900817779268f

__device__ __forceinline__ int lower_bound_i(const int* a, int n, int key) {
    int lo = 0, hi = n;
    while (lo < hi) { int mid = (lo + hi) >> 1; if (a[mid] < key) lo = mid + 1; else hi = mid; }
    return lo;
}

__device__ __forceinline__ unsigned bf16rne(float f) {
    unsigned u = __float_as_uint(f);
    return (u + 0x7fffu + ((u >> 16) & 1u)) >> 16;
}

__device__ __forceinline__ unsigned sel8u(unsigned a0, unsigned a1, unsigned a2, unsigned a3,
                                          unsigned a4, unsigned a5, unsigned a6, unsigned a7, int i) {
    unsigned b0 = (i & 1) ? a1 : a0, b1 = (i & 1) ? a3 : a2;
    unsigned b2 = (i & 1) ? a5 : a4, b3 = (i & 1) ? a7 : a6;
    unsigned c0 = (i & 2) ? b1 : b0, c1 = (i & 2) ? b3 : b2;
    return (i & 4) ? c1 : c0;
}
__device__ __forceinline__ int sel8i(int a0, int a1, int a2, int a3,
                                     int a4, int a5, int a6, int a7, int i) {
    int b0 = (i & 1) ? a1 : a0, b1 = (i & 1) ? a3 : a2;
    int b2 = (i & 1) ? a5 : a4, b3 = (i & 1) ? a7 : a6;
    int c0 = (i & 2) ? b1 : b0, c1 = (i & 2) ? b3 : b2;
    return (i & 4) ? c1 : c0;
}

// ---------------- projection section descriptor ----------------
struct ProjSec {
    const float* x; const float* Wa; const float* ba;
    const float* Wb; const float* bb2; unsigned* out;
    int N; int waveOff; float scaleA;
};
#define PROJ_ROWS 16

// ---------------- fused histogram + projections ----------------
__global__ __launch_bounds__(256) void hist_proj_kernel(
    const int* __restrict__ dst0, int E0,
    const int* __restrict__ dst1, int E1n, int dstOff1,
    int* __restrict__ cnt, int histBlocks,
    ProjSec s0, ProjSec s1, ProjSec s2, ProjSec s3, int wTot)
{
    if ((int)blockIdx.x < histBlocks) {
        int i = blockIdx.x * blockDim.x + threadIdx.x;
        if (i < E0) {
            atomicAdd(&cnt[dst0[i]], 1);
        } else {
            i -= E0;
            if (i < E1n) atomicAdd(&cnt[dstOff1 + dst1[i]], 1);
        }
        return;
    }
    const int lane = threadIdx.x & 63;
    const int w = (blockIdx.x - histBlocks) * (blockDim.x >> 6) + (threadIdx.x >> 6);
    if (w >= wTot) return;
    ProjSec S = (w >= s3.waveOff) ? s3 : (w >= s2.waveOff) ? s2 : (w >= s1.waveOff) ? s1 : s0;
    const int r0 = (w - S.waveOff) * PROJ_ROWS;
    float wa[F], wb[F];
#pragma unroll
    for (int f = 0; f < F; ++f) {
        wa[f] = S.Wa[f * H + lane] * S.scaleA;
        wb[f] = S.Wb[f * H + lane];
    }
    const float bah = S.ba[lane] * S.scaleA, bbh = S.bb2[lane];
    int r1e = r0 + PROJ_ROWS; if (r1e > S.N) r1e = S.N;
    for (int n = r0; n < r1e; ++n) {
        const float4* xr = (const float4*)(S.x + (size_t)n * F);
        float a = bah, b = bbh;
#pragma unroll
        for (int f4 = 0; f4 < F / 4; ++f4) {
            float4 t = xr[f4];
            a = fmaf(t.x, wa[4*f4+0], a); a = fmaf(t.y, wa[4*f4+1], a);
            a = fmaf(t.z, wa[4*f4+2], a); a = fmaf(t.w, wa[4*f4+3], a);
            b = fmaf(t.x, wb[4*f4+0], b); b = fmaf(t.y, wb[4*f4+1], b);
            b = fmaf(t.z, wb[4*f4+2], b); b = fmaf(t.w, wb[4*f4+3], b);
        }
        S.out[(size_t)n * H + lane] = bf16rne(a) | (bf16rne(b) << 16);
    }
}

// ---------------- scan ----------------
__global__ __launch_bounds__(256) void scan_partial(const int* __restrict__ cnt,
                                                    int* __restrict__ bsums, int n) {
    __shared__ int red[256];
    const int b = blockIdx.x, t = threadIdx.x;
    const int base = b * 2048 + t * 8;
    int s = 0;
#pragma unroll
    for (int i = 0; i < 8; ++i) { int idx = base + i; if (idx < n) s += cnt[idx]; }
    red[t] = s;
    __syncthreads();
    for (int off = 128; off > 0; off >>= 1) {
        if (t < off) red[t] += red[t + off];
        __syncthreads();
    }
    if (t == 0) bsums[b] = red[0];
}

__global__ __launch_bounds__(256) void scan_bsums(int* __restrict__ bsums, int nb) {
    __shared__ int sh[256];
    const int t = threadIdx.x;
    sh[t] = (t < nb) ? bsums[t] : 0;
    __syncthreads();
    for (int off = 1; off < 256; off <<= 1) {
        int v = sh[t];
        int add = (t >= off) ? sh[t - off] : 0;
        __syncthreads();
        sh[t] = v + add;
        __syncthreads();
    }
    if (t < nb) bsums[t] = (t == 0) ? 0 : sh[t - 1];
}

// writes offsets[idx]=prefix AND cnt[idx]=prefix (cursor init, in place)
__global__ __launch_bounds__(256) void scan_final(int* __restrict__ cnt,
                                                  const int* __restrict__ bsums,
                                                  int* __restrict__ offsets, int n) {
    __shared__ int red[256];
    const int b = blockIdx.x, t = threadIdx.x;
    const int base = b * 2048 + t * 8;
    int v[8]; int s = 0;
#pragma unroll
    for (int i = 0; i < 8; ++i) { int idx = base + i; v[i] = (idx < n) ? cnt[idx] : 0; s += v[i]; }
    red[t] = s;
    __syncthreads();
    for (int off = 1; off < 256; off <<= 1) {
        int val = red[t];
        int add = (t >= off) ? red[t - off] : 0;
        __syncthreads();
        red[t] = val + add;
        __syncthreads();
    }
    const int ex = (t == 0) ? 0 : red[t - 1];
    int run = bsums[b] + ex;
#pragma unroll
    for (int i = 0; i < 8; ++i) {
        int idx = base + i;
        if (idx < n) { offsets[idx] = run; cnt[idx] = run; }
        run += v[i];
    }
    if (t == 255 && b == gridDim.x - 1) offsets[n] = run;
}

// cursor pre-initialized to offsets; atomicAdd returns absolute slot
__global__ __launch_bounds__(256) void scatter2_kernel(
    const int* __restrict__ src0, const int* __restrict__ dst0,
    const float* __restrict__ ea0, int E0,
    const int* __restrict__ src1, const int* __restrict__ dst1,
    const float* __restrict__ ea1, int E1n,
    int dstOff1, int srcOff1,
    int* __restrict__ cursor, int2* __restrict__ meta) {
    int i = blockIdx.x * blockDim.x + threadIdx.x;
    if (i < E0) {
        int d = dst0[i];
        int p = atomicAdd(&cursor[d], 1);
        meta[p] = make_int2(src0[i], __float_as_int(ea0[i]));
    } else {
        i -= E0;
        if (i < E1n) {
            int d = dstOff1 + dst1[i];
            int p = atomicAdd(&cursor[d], 1);
            meta[p] = make_int2(src1[i] + srcOff1, __float_as_int(ea1[i]));
        }
    }
}

// ---------------- deep-pipelined streaming aggregate ----------------
struct RelP {
    const float* We; const float* be;
    const int* batch;
    float* psum;
    int Ndst;
    int offBase;
    int kskBase;
};

__global__ __launch_bounds__(256) void aggregate_v4(
    RelP P0, RelP P1, const unsigned* __restrict__ qvp,
    const unsigned* __restrict__ kskp,
    const int* __restrict__ offsets, const int2* __restrict__ meta,
    int nChunk0, int chunkHi)
{
    const int lane = threadIdx.x & 63;
    const int cid = blockIdx.x * (blockDim.x >> 6) + (threadIdx.x >> 6);
    if (cid >= chunkHi) return;
    const bool r1v = (cid >= nChunk0);
    const RelP P = r1v ? P1 : P0;
    const int dLo = (r1v ? cid - nChunk0 : cid) * DPW;
    if (dLo >= P.Ndst) return;
    const int ndst = (P.Ndst - dLo < DPW) ? (P.Ndst - dLo) : DPW;

    const float weh = P.We[lane], beh = P.be[lane];

    // scalar chunk bounds + graph ids
    const int* ob = offsets + P.offBase + dLo;
    const int* bb_ = P.batch + dLo;
    int of0, of1, of2, of3, of4, of5, of6, of7, of8;
    int bg0, bg1, bg2, bg3, bg4, bg5, bg6, bg7;
#define LDO(I) __builtin_amdgcn_readfirstlane(ob[(I) < ndst ? (I) : ndst])
#define LDB(I) __builtin_amdgcn_readfirstlane(bb_[(I) < ndst ? (I) : (ndst - 1)])
    of0 = LDO(0); of1 = LDO(1); of2 = LDO(2); of3 = LDO(3); of4 = LDO(4);
    of5 = LDO(5); of6 = LDO(6); of7 = LDO(7); of8 = LDO(8);
    bg0 = LDB(0); bg1 = LDB(1); bg2 = LDB(2); bg3 = LDB(3);
    bg4 = LDB(4); bg5 = LDB(5); bg6 = LDB(6); bg7 = LDB(7);
#undef LDO
#undef LDB

    // packed (k', sk) rows
    const unsigned* kb = kskp + (size_t)(P.kskBase + dLo) * H + lane;
    unsigned kp0 = kb[0], kp1 = 0, kp2 = 0, kp3 = 0, kp4 = 0, kp5 = 0, kp6 = 0, kp7 = 0;
    if (ndst > 1) kp1 = kb[1 * H];
    if (ndst > 2) kp2 = kb[2 * H];
    if (ndst > 3) kp3 = kb[3 * H];
    if (ndst > 4) kp4 = kb[4 * H];
    if (ndst > 5) kp5 = kb[5 * H];
    if (ndst > 6) kp6 = kb[6 * H];
    if (ndst > 7) kp7 = kb[7 * H];

    int idx = 0;
    float kcur = __uint_as_float(kp0 << 16);
    float skcur = __uint_as_float(kp0 & 0xffff0000u);
    int pend = of1;
    int bgcur = bg0;
    float acc = 0.f;
    const int base = of0;
    const int pstop = of8;
    const int nedges = pstop - base;
    const int ngroups = (nedges + 7) >> 3;

#define ADVANCE()                                                              \
    {                                                                          \
        float hv = fmaxf(acc + skcur, 0.f);                                    \
        atomicAdd(&P.psum[(size_t)bgcur * H + lane], hv);                      \
        ++idx;                                                                 \
        unsigned kv = sel8u(kp0, kp1, kp2, kp3, kp4, kp5, kp6, kp7, idx);      \
        kcur = __uint_as_float(kv << 16);                                      \
        skcur = __uint_as_float(kv & 0xffff0000u);                             \
        pend = sel8i(of1, of2, of3, of4, of5, of6, of7, of8, idx);             \
        bgcur = sel8i(bg0, bg1, bg2, bg3, bg4, bg5, bg6, bg7, idx);            \
        acc = 0.f;                                                             \
    }

    // issue group gI's gathers from meta regs M (readlane, scalar base)
#define ISSUE(RING, M, L8, GI)                                                 \
    if ((GI) < ngroups) {                                                      \
        _Pragma("unroll")                                                      \
        for (int j = 0; j < 8; ++j) {                                          \
            int s_ = __builtin_amdgcn_readlane((M).x, (L8) + j);               \
            RING[j] = qvp[(size_t)(unsigned)s_ * H + lane];                    \
        }                                                                      \
    }

#define CONSUME(RING, L8, GI)                                                  \
    if ((GI) < ngroups) {                                                      \
        const int e0 = (GI) * 8;                                               \
        int n_ = nedges - e0; if (n_ > 8) n_ = 8;                              \
        _Pragma("unroll")                                                      \
        for (int j = 0; j < 8; ++j) {                                          \
            if (j < n_) {                                                      \
                while (base + e0 + j >= pend) ADVANCE();                       \
                float e = fmaf(__int_as_float(                                 \
                    __builtin_amdgcn_readlane(Mc.y, (L8) + j)), weh, beh);     \
                float qq = __uint_as_float(RING[j] << 16);                     \
                float vv = __uint_as_float(RING[j] & 0xffff0000u);             \
                float g2 = fmaf(TWO_L2E, e, kcur + qq);                        \
                float sg = __builtin_amdgcn_rcpf(1.0f + __builtin_amdgcn_exp2f(-g2)); \
                acc = fmaf(sg, vv + e, acc);                                   \
            }                                                                  \
        }                                                                      \
    }

    if (nedges > 0) {
        // wave-cooperative meta superbatches: one int2/lane = 64 edges
        int pos0 = base + lane; if (pos0 > pstop - 1) pos0 = pstop - 1;
        int2 Mc = meta[pos0];
        int2 Mn = Mc;
        if (nedges > 64) {
            int pos1 = base + 64 + lane; if (pos1 > pstop - 1) pos1 = pstop - 1;
            Mn = meta[pos1];
        }
        unsigned r0[8], r1[8], r2[8], r3[8];
        ISSUE(r0, Mc, 0, 0);
        ISSUE(r1, Mc, 8, 1);
        const int nsb = (ngroups + 7) >> 3;
        int sbg = 0;
        for (int sbi = 0; sbi < nsb; ++sbi, sbg += 8) {
            ISSUE(r2, Mc, 16, sbg + 2); CONSUME(r0, 0,  sbg + 0);
            ISSUE(r3, Mc, 24, sbg + 3); CONSUME(r1, 8,  sbg + 1);
            ISSUE(r0, Mc, 32, sbg + 4); CONSUME(r2, 16, sbg + 2);
            ISSUE(r1, Mc, 40, sbg + 5); CONSUME(r3, 24, sbg + 3);
            ISSUE(r2, Mc, 48, sbg + 6); CONSUME(r0, 32, sbg + 4);
            ISSUE(r3, Mc, 56, sbg + 7); CONSUME(r1, 40, sbg + 5);
            ISSUE(r0, Mn, 0,  sbg + 8); CONSUME(r2, 48, sbg + 6);
            ISSUE(r1, Mn, 8,  sbg + 9); CONSUME(r3, 56, sbg + 7);
            Mc = Mn;
            if ((sbi + 2) * 64 < nedges) {
                int pos = base + (sbi + 2) * 64 + lane;
                if (pos > pstop - 1) pos = pstop - 1;
                Mn = meta[pos];
            }
        }
    }
#undef ISSUE
#undef CONSUME

    // flush current dst, then trailing (possibly empty) dsts
    for (;;) {
        float hv = fmaxf(acc + skcur, 0.f);
        atomicAdd(&P.psum[(size_t)bgcur * H + lane], hv);
        ++idx;
        if (idx >= ndst) break;
        unsigned kv = sel8u(kp0, kp1, kp2, kp3, kp4, kp5, kp6, kp7, idx);
        kcur = __uint_as_float(kv << 16);
        skcur = __uint_as_float(kv & 0xffff0000u);
        bgcur = sel8i(bg0, bg1, bg2, bg3, bg4, bg5, bg6, bg7, idx);
        acc = 0.f;
    }
#undef ADVANCE
}

// ---------------- MLP with fused per-graph counts ----------------
__global__ __launch_bounds__(64) void mlp_kernel(
    const float* __restrict__ sum_c, const float* __restrict__ sum_b,
    const int* __restrict__ batch_c, int Nc,
    const int* __restrict__ batch_b, int Nb,
    const float* __restrict__ W1, const float* __restrict__ b1,
    const float* __restrict__ W2, const float* __restrict__ b2,
    const float* __restrict__ W3, const float* __restrict__ b3,
    const float* __restrict__ Wout, const float* __restrict__ bout,
    float* __restrict__ out)
{
    const int g = blockIdx.x;
    const int h = threadIdx.x;
    __shared__ float pld[2 * H];
    __shared__ float hbuf[H];
    __shared__ float cnts[2];
    if (h < 2) {
        const int* a = h ? batch_b : batch_c;
        const int n = h ? Nb : Nc;
        int lo = lower_bound_i(a, n, g);
        int hi = lower_bound_i(a, n, g + 1);
        cnts[h] = fmaxf((float)(hi - lo), 1.f);
    }
    __syncthreads();
    pld[h] = sum_c[g * H + h] / cnts[0];
    pld[H + h] = sum_b[g * H + h] / cnts[1];
    __syncthreads();
    float a1 = b1[h];
    for (int j = 0; j < 2 * H; ++j) a1 = fmaf(pld[j], W1[j * H + h], a1);
    a1 = fmaxf(a1, 0.f);
    __syncthreads();
    hbuf[h] = a1;
    __syncthreads();
    float a2 = b2[h];
    for (int j = 0; j < H; ++j) a2 = fmaf(hbuf[j], W2[j * H + h], a2);
    a2 = fmaxf(a2, 0.f);
    __syncthreads();
    hbuf[h] = a2;
    __syncthreads();
    float a3 = b3[h];
    for (int j = 0; j < H; ++j) a3 = fmaf(hbuf[j], W3[j * H + h], a3);
    a3 = fmaxf(a3, 0.f);
    float p = a3 * Wout[h];
#pragma unroll
    for (int off = 32; off > 0; off >>= 1) p += __shfl_down(p, off, 64);
    if (h == 0) out[g] = p + bout[0];
}

extern "C" void kernel_launch(void* const* d_in, const int* in_sizes, int n_in,
                              void* d_out, int out_size, void* d_ws, size_t ws_size,
                              hipStream_t stream) {
    const float* x_x   = (const float*)d_in[0];
    const float* x_c   = (const float*)d_in[1];
    const float* x_b   = (const float*)d_in[2];
    const float* ea_ac = (const float*)d_in[3];
    const float* ea_cb = (const float*)d_in[4];

    const float* Wk_ac = (const float*)d_in[5];
    const float* Wq_ac = (const float*)d_in[6];
    const float* Wv_ac = (const float*)d_in[7];
    const float* Wskip_ac = (const float*)d_in[8];
    const float* We_ac = (const float*)d_in[9];
    const float* bk_ac = (const float*)d_in[10];
    const float* bq_ac = (const float*)d_in[11];
    const float* bv_ac = (const float*)d_in[12];
    const float* be_ac = (const float*)d_in[13];
    const float* bconv_ac = (const float*)d_in[14];

    const float* Wk_cb = (const float*)d_in[15];
    const float* Wq_cb = (const float*)d_in[16];
    const float* Wv_cb = (const float*)d_in[17];
    const float* Wskip_cb = (const float*)d_in[18];
    const float* We_cb = (const float*)d_in[19];
    const float* bk_cb = (const float*)d_in[20];
    const float* bq_cb = (const float*)d_in[21];
    const float* bv_cb = (const float*)d_in[22];
    const float* be_cb = (const float*)d_in[23];
    const float* bconv_cb = (const float*)d_in[24];

    const float* W1 = (const float*)d_in[25];
    const float* b1 = (const float*)d_in[26];
    const float* W2 = (const float*)d_in[27];
    const float* b2 = (const float*)d_in[28];
    const float* W3 = (const float*)d_in[29];
    const float* b3 = (const float*)d_in[30];
    const float* Wout = (const float*)d_in[31];
    const float* bout = (const float*)d_in[32];

    const int* src_ac = (const int*)d_in[33];
    const int* dst_ac = (const int*)d_in[34];
    const int* src_cb = (const int*)d_in[35];
    const int* dst_cb = (const int*)d_in[36];
    const int* batch_c = (const int*)d_in[37];
    const int* batch_b = (const int*)d_in[38];

    const int Nx = in_sizes[0] / F;
    const int Nc = in_sizes[1] / F;
    const int Nb = in_sizes[2] / F;
    const int E1 = in_sizes[33];
    const int E2 = in_sizes[35];
    (void)n_in; (void)out_size;

    const int NT = Nc + Nb;
    const size_t ET = (size_t)E1 + E2;
    const int NMAX = (Nc > Nb ? Nc : Nb);
    const int EMAX = (E1 > E2 ? E1 : E2);
    const int SRCMAX = (Nx > Nc ? Nx : Nc);
    const size_t SUMS = 2 * NUM_G * H;

    const size_t wordsA = 2 * ET + (size_t)(NT + 1) + NT + 256 + SUMS
                        + (size_t)(Nx + Nc) * H + (size_t)(Nc + Nb) * H;
    const bool pathA = (ws_size >= wordsA * 4);

    int* ws = (int*)d_ws;
    const size_t metaN = pathA ? 2 * ET : 2 * (size_t)EMAX;
    const int nOff = pathA ? NT : NMAX;
    int2*     meta    = (int2*)ws;
    int*      offsets = ws + metaN;
    int*      cnt     = offsets + (nOff + 1);
    int*      bsums   = cnt + nOff;
    float*    sum_c   = (float*)(bsums + 256);
    float*    sum_b   = sum_c + NUM_G * H;
    unsigned* qvp     = (unsigned*)(sum_b + NUM_G * H);
    unsigned* kskp    = qvp + (size_t)(pathA ? (Nx + Nc) : SRCMAX) * H;

    const int nC0 = (Nc + DPW - 1) / DPW;
    const int nC1 = (Nb + DPW - 1) / DPW;

    RelP P0, P1;
    P0.We = We_ac; P0.be = be_ac; P0.batch = batch_c; P0.psum = sum_c;
    P0.Ndst = Nc; P0.offBase = 0; P0.kskBase = 0;
    P1.We = We_cb; P1.be = be_cb; P1.batch = batch_b; P1.psum = sum_b;
    P1.Ndst = Nb; P1.offBase = pathA ? Nc : 0; P1.kskBase = pathA ? Nc : 0;

    if (pathA) {
        // one memset covers cnt | bsums | sum_c | sum_b (contiguous)
        hipMemsetAsync(cnt, 0, (size_t)(NT + 256 + SUMS) * sizeof(int), stream);

        const int nScan = (NT + 2047) / 2048;
        const int EB = (int)((ET + 255) / 256);
        const int w1 = (Nx + PROJ_ROWS - 1) / PROJ_ROWS;
        const int w2 = w1 + (Nc + PROJ_ROWS - 1) / PROJ_ROWS;
        const int w3 = w2 + (Nc + PROJ_ROWS - 1) / PROJ_ROWS;
        const int wTot = w3 + (Nb + PROJ_ROWS - 1) / PROJ_ROWS;
        ProjSec s0 = { x_x, Wq_ac, bq_ac, Wv_ac, bv_ac, qvp, Nx, 0, L2E };
        ProjSec s1 = { x_c, Wq_cb, bq_cb, Wv_cb, bv_cb, qvp + (size_t)Nx * H, Nc, w1, L2E };
        ProjSec s2 = { x_c, Wk_ac, bk_ac, Wskip_ac, bconv_ac, kskp, Nc, w2, L2E };
        ProjSec s3 = { x_b, Wk_cb, bk_cb, Wskip_cb, bconv_cb, kskp + (size_t)Nc * H, Nb, w3, L2E };
        const int projB = (wTot + 3) / 4;

        hist_proj_kernel<<<EB + projB, 256, 0, stream>>>(
            dst_ac, E1, dst_cb, E2, Nc, cnt, EB, s0, s1, s2, s3, wTot);
        scan_partial<<<nScan, 256, 0, stream>>>(cnt, bsums, NT);
        scan_bsums<<<1, 256, 0, stream>>>(bsums, nScan);
        scan_final<<<nScan, 256, 0, stream>>>(cnt, bsums, offsets, NT);
        scatter2_kernel<<<EB, 256, 0, stream>>>(
            src_ac, dst_ac, ea_ac, E1, src_cb, dst_cb, ea_cb, E2,
            Nc, Nx, cnt, meta);

        const int nW = nC0 + nC1;
        aggregate_v4<<<(nW + 3) / 4, 256, 0, stream>>>(
            P0, P1, qvp, kskp, offsets, meta, nC0, nW);
    } else {
        hipMemsetAsync(sum_c, 0, SUMS * sizeof(float), stream);
        for (int rel = 0; rel < 2; ++rel) {
            const int n = rel ? Nb : Nc;
            const int E = rel ? E2 : E1;
            const int Ns = rel ? Nc : Nx;
            const int* srcA = rel ? src_cb : src_ac;
            const int* dstA = rel ? dst_cb : dst_ac;
            const float* eaA = rel ? ea_cb : ea_ac;
            const float* xs = rel ? x_c : x_x;
            const float* xd = rel ? x_b : x_c;
            const float* Wq = rel ? Wq_cb : Wq_ac; const float* bq = rel ? bq_cb : bq_ac;
            const float* Wv = rel ? Wv_cb : Wv_ac; const float* bv = rel ? bv_cb : bv_ac;
            const float* Wk = rel ? Wk_cb : Wk_ac; const float* bk = rel ? bk_cb : bk_ac;
            const float* Wsk = rel ? Wskip_cb : Wskip_ac;
            const float* bcv = rel ? bconv_cb : bconv_ac;
            const int nScan = (n + 2047) / 2048;
            hipMemsetAsync(cnt, 0, n * sizeof(int), stream);
            const int w1 = (Ns + PROJ_ROWS - 1) / PROJ_ROWS;
            const int wTot = w1 + (n + PROJ_ROWS - 1) / PROJ_ROWS;
            ProjSec s0 = { xs, Wq, bq, Wv, bv, qvp, Ns, 0, L2E };
            ProjSec s1 = { xs, Wq, bq, Wv, bv, qvp, 0, w1, L2E };
            ProjSec s2 = { xd, Wk, bk, Wsk, bcv, kskp, n, w1, L2E };
            ProjSec s3 = { xd, Wk, bk, Wsk, bcv, kskp, 0, wTot, L2E };
            const int EB = (E + 255) / 256;
            const int projB = (wTot + 3) / 4;
            hist_proj_kernel<<<EB + projB, 256, 0, stream>>>(
                dstA, E, dstA, 0, 0, cnt, EB, s0, s1, s2, s3, wTot);
            scan_partial<<<nScan, 256, 0, stream>>>(cnt, bsums, n);
            scan_bsums<<<1, 256, 0, stream>>>(bsums, nScan);
            scan_final<<<nScan, 256, 0, stream>>>(cnt, bsums, offsets, n);
            scatter2_kernel<<<EB, 256, 0, stream>>>(
                srcA, dstA, eaA, E, srcA, dstA, eaA, 0, 0, 0, cnt, meta);
            RelP PR = rel ? P1 : P0;
            const int nCr = rel ? nC1 : nC0;
            aggregate_v4<<<(nCr + 3) / 4, 256, 0, stream>>>(
                PR, PR, qvp, kskp, offsets, meta, nCr, nCr);
        }
    }

    mlp_kernel<<<NUM_G, 64, 0, stream>>>(
        sum_c, sum_b, batch_c, Nc, batch_b, Nb,
        W1, b1, W2, b2, W3, b3, Wout, bout, (float*)d_out);
}

// Round 8
// 657.671 us; speedup vs baseline: 2.7464x; 1.0790x over previous
//
#include <hip/hip_runtime.h>
#include <math.h>

#define H 64
#define F 16
#define NUM_G 128
#define DPW 8   // dsts per wave chunk
#define L2E 1.4426950408889634f
#define TWO_L2E 2.8853900817779268f

__device__ __forceinline__ int lower_bound_i(const int* a, int n, int key) {
    int lo = 0, hi = n;
    while (lo < hi) { int mid = (lo + hi) >> 1; if (a[mid] < key) lo = mid + 1; else hi = mid; }
    return lo;
}

__device__ __forceinline__ unsigned bf16rne(float f) {
    unsigned u = __float_as_uint(f);
    return (u + 0x7fffu + ((u >> 16) & 1u)) >> 16;
}

__device__ __forceinline__ unsigned sel8u(unsigned a0, unsigned a1, unsigned a2, unsigned a3,
                                          unsigned a4, unsigned a5, unsigned a6, unsigned a7, int i) {
    unsigned b0 = (i & 1) ? a1 : a0, b1 = (i & 1) ? a3 : a2;
    unsigned b2 = (i & 1) ? a5 : a4, b3 = (i & 1) ? a7 : a6;
    unsigned c0 = (i & 2) ? b1 : b0, c1 = (i & 2) ? b3 : b2;
    return (i & 4) ? c1 : c0;
}
__device__ __forceinline__ int sel8i(int a0, int a1, int a2, int a3,
                                     int a4, int a5, int a6, int a7, int i) {
    int b0 = (i & 1) ? a1 : a0, b1 = (i & 1) ? a3 : a2;
    int b2 = (i & 1) ? a5 : a4, b3 = (i & 1) ? a7 : a6;
    int c0 = (i & 2) ? b1 : b0, c1 = (i & 2) ? b3 : b2;
    return (i & 4) ? c1 : c0;
}

// ---------------- projection section descriptor ----------------
struct ProjSec {
    const float* x; const float* Wa; const float* ba;
    const float* Wb; const float* bb2; unsigned* out;
    int N; int waveOff; float scaleA;
};
#define PROJ_ROWS 16

// ---------------- fused histogram + projections ----------------
__global__ __launch_bounds__(256) void hist_proj_kernel(
    const int* __restrict__ dst0, int E0,
    const int* __restrict__ dst1, int E1n, int dstOff1,
    int* __restrict__ cnt, int histBlocks,
    ProjSec s0, ProjSec s1, ProjSec s2, ProjSec s3, int wTot)
{
    if ((int)blockIdx.x < histBlocks) {
        int i = blockIdx.x * blockDim.x + threadIdx.x;
        if (i < E0) {
            atomicAdd(&cnt[dst0[i]], 1);
        } else {
            i -= E0;
            if (i < E1n) atomicAdd(&cnt[dstOff1 + dst1[i]], 1);
        }
        return;
    }
    const int lane = threadIdx.x & 63;
    const int w = (blockIdx.x - histBlocks) * (blockDim.x >> 6) + (threadIdx.x >> 6);
    if (w >= wTot) return;
    ProjSec S = (w >= s3.waveOff) ? s3 : (w >= s2.waveOff) ? s2 : (w >= s1.waveOff) ? s1 : s0;
    const int r0 = (w - S.waveOff) * PROJ_ROWS;
    float wa[F], wb[F];
#pragma unroll
    for (int f = 0; f < F; ++f) {
        wa[f] = S.Wa[f * H + lane] * S.scaleA;
        wb[f] = S.Wb[f * H + lane];
    }
    const float bah = S.ba[lane] * S.scaleA, bbh = S.bb2[lane];
    int r1e = r0 + PROJ_ROWS; if (r1e > S.N) r1e = S.N;
    for (int n = r0; n < r1e; ++n) {
        const float4* xr = (const float4*)(S.x + (size_t)n * F);
        float a = bah, b = bbh;
#pragma unroll
        for (int f4 = 0; f4 < F / 4; ++f4) {
            float4 t = xr[f4];
            a = fmaf(t.x, wa[4*f4+0], a); a = fmaf(t.y, wa[4*f4+1], a);
            a = fmaf(t.z, wa[4*f4+2], a); a = fmaf(t.w, wa[4*f4+3], a);
            b = fmaf(t.x, wb[4*f4+0], b); b = fmaf(t.y, wb[4*f4+1], b);
            b = fmaf(t.z, wb[4*f4+2], b); b = fmaf(t.w, wb[4*f4+3], b);
        }
        S.out[(size_t)n * H + lane] = bf16rne(a) | (bf16rne(b) << 16);
    }
}

// ---------------- scan ----------------
__global__ __launch_bounds__(256) void scan_partial(const int* __restrict__ cnt,
                                                    int* __restrict__ bsums, int n) {
    __shared__ int red[256];
    const int b = blockIdx.x, t = threadIdx.x;
    const int base = b * 2048 + t * 8;
    int s = 0;
#pragma unroll
    for (int i = 0; i < 8; ++i) { int idx = base + i; if (idx < n) s += cnt[idx]; }
    red[t] = s;
    __syncthreads();
    for (int off = 128; off > 0; off >>= 1) {
        if (t < off) red[t] += red[t + off];
        __syncthreads();
    }
    if (t == 0) bsums[b] = red[0];
}

__global__ __launch_bounds__(256) void scan_bsums(int* __restrict__ bsums, int nb) {
    __shared__ int sh[256];
    const int t = threadIdx.x;
    sh[t] = (t < nb) ? bsums[t] : 0;
    __syncthreads();
    for (int off = 1; off < 256; off <<= 1) {
        int v = sh[t];
        int add = (t >= off) ? sh[t - off] : 0;
        __syncthreads();
        sh[t] = v + add;
        __syncthreads();
    }
    if (t < nb) bsums[t] = (t == 0) ? 0 : sh[t - 1];
}

// writes offsets[idx]=prefix AND cnt[idx]=prefix (cursor init, in place)
__global__ __launch_bounds__(256) void scan_final(int* __restrict__ cnt,
                                                  const int* __restrict__ bsums,
                                                  int* __restrict__ offsets, int n) {
    __shared__ int red[256];
    const int b = blockIdx.x, t = threadIdx.x;
    const int base = b * 2048 + t * 8;
    int v[8]; int s = 0;
#pragma unroll
    for (int i = 0; i < 8; ++i) { int idx = base + i; v[i] = (idx < n) ? cnt[idx] : 0; s += v[i]; }
    red[t] = s;
    __syncthreads();
    for (int off = 1; off < 256; off <<= 1) {
        int val = red[t];
        int add = (t >= off) ? red[t - off] : 0;
        __syncthreads();
        red[t] = val + add;
        __syncthreads();
    }
    const int ex = (t == 0) ? 0 : red[t - 1];
    int run = bsums[b] + ex;
#pragma unroll
    for (int i = 0; i < 8; ++i) {
        int idx = base + i;
        if (idx < n) { offsets[idx] = run; cnt[idx] = run; }
        run += v[i];
    }
    if (t == 255 && b == gridDim.x - 1) offsets[n] = run;
}

// ---------------- XCD-partitioned scatter ----------------
// Block b: grp = b&7 (~XCD via round-robin dispatch), seg = b>>3.
// Group g OWNS dst range [g*per, min((g+1)*per, NTd)); it streams the edge
// segment with nontemporal loads and writes only owned edges, so each meta
// line is assembled inside one XCD's L2 and flushed once.
__device__ __forceinline__ void scat_sub(
    const int* __restrict__ src, const int* __restrict__ dst,
    const float* __restrict__ ea, long lo, long hi,
    int dstOff, int srcOff, int dlo, int dhi,
    int* __restrict__ cursor, int2* __restrict__ meta, int tid)
{
    for (long i = lo + tid; i < hi; i += 256) {
        int d = dstOff + __builtin_nontemporal_load(dst + i);
        if (d >= dlo && d < dhi) {
            int s = __builtin_nontemporal_load(src + i) + srcOff;
            float e = __builtin_nontemporal_load(ea + i);
            int p = atomicAdd(&cursor[d], 1);
            meta[p] = make_int2(s, __float_as_int(e));
        }
    }
}

__global__ __launch_bounds__(256) void scatter_part_kernel(
    const int* __restrict__ src0, const int* __restrict__ dst0,
    const float* __restrict__ ea0, int E0,
    const int* __restrict__ src1, const int* __restrict__ dst1,
    const float* __restrict__ ea1, int E1n,
    int dstOff1, int srcOff1, int NTd,
    int* __restrict__ cursor, int2* __restrict__ meta)
{
    const int grp = blockIdx.x & 7;
    const int seg = blockIdx.x >> 3;
    const int nseg = gridDim.x >> 3;
    const int per = (NTd + 7) >> 3;
    const int dlo = grp * per;
    int dhi = dlo + per; if (dhi > NTd) dhi = NTd;
    if (dlo >= dhi) return;
    const long ET = (long)E0 + E1n;
    const long e0 = (ET * seg) / nseg;
    const long e1 = (ET * (seg + 1)) / nseg;
    const int tid = threadIdx.x;
    // overlap with relation 0: [0, E0)
    long a0 = e0, a1 = (e1 < E0) ? e1 : E0;
    if (a0 < a1) scat_sub(src0, dst0, ea0, a0, a1, 0, 0, dlo, dhi, cursor, meta, tid);
    // overlap with relation 1: [E0, ET)
    long b0 = (e0 > E0) ? e0 : E0, b1 = e1;
    if (b0 < b1) scat_sub(src1, dst1, ea1, b0 - E0, b1 - E0, dstOff1, srcOff1,
                          dlo, dhi, cursor, meta, tid);
}

// ---------------- deep-pipelined streaming aggregate ----------------
struct RelP {
    const float* We; const float* be;
    const int* batch;
    float* psum;
    int Ndst;
    int offBase;
    int kskBase;
};

__global__ __launch_bounds__(256) void aggregate_v4(
    RelP P0, RelP P1, const unsigned* __restrict__ qvp,
    const unsigned* __restrict__ kskp,
    const int* __restrict__ offsets, const int2* __restrict__ meta,
    int nChunk0, int chunkHi)
{
    const int lane = threadIdx.x & 63;
    const int cid = blockIdx.x * (blockDim.x >> 6) + (threadIdx.x >> 6);
    if (cid >= chunkHi) return;
    const bool r1v = (cid >= nChunk0);
    const RelP P = r1v ? P1 : P0;
    const int dLo = (r1v ? cid - nChunk0 : cid) * DPW;
    if (dLo >= P.Ndst) return;
    const int ndst = (P.Ndst - dLo < DPW) ? (P.Ndst - dLo) : DPW;

    const float weh = P.We[lane], beh = P.be[lane];

    const int* ob = offsets + P.offBase + dLo;
    const int* bb_ = P.batch + dLo;
    int of0, of1, of2, of3, of4, of5, of6, of7, of8;
    int bg0, bg1, bg2, bg3, bg4, bg5, bg6, bg7;
#define LDO(I) __builtin_amdgcn_readfirstlane(ob[(I) < ndst ? (I) : ndst])
#define LDB(I) __builtin_amdgcn_readfirstlane(bb_[(I) < ndst ? (I) : (ndst - 1)])
    of0 = LDO(0); of1 = LDO(1); of2 = LDO(2); of3 = LDO(3); of4 = LDO(4);
    of5 = LDO(5); of6 = LDO(6); of7 = LDO(7); of8 = LDO(8);
    bg0 = LDB(0); bg1 = LDB(1); bg2 = LDB(2); bg3 = LDB(3);
    bg4 = LDB(4); bg5 = LDB(5); bg6 = LDB(6); bg7 = LDB(7);
#undef LDO
#undef LDB

    const unsigned* kb = kskp + (size_t)(P.kskBase + dLo) * H + lane;
    unsigned kp0 = kb[0], kp1 = 0, kp2 = 0, kp3 = 0, kp4 = 0, kp5 = 0, kp6 = 0, kp7 = 0;
    if (ndst > 1) kp1 = kb[1 * H];
    if (ndst > 2) kp2 = kb[2 * H];
    if (ndst > 3) kp3 = kb[3 * H];
    if (ndst > 4) kp4 = kb[4 * H];
    if (ndst > 5) kp5 = kb[5 * H];
    if (ndst > 6) kp6 = kb[6 * H];
    if (ndst > 7) kp7 = kb[7 * H];

    int idx = 0;
    float kcur = __uint_as_float(kp0 << 16);
    float skcur = __uint_as_float(kp0 & 0xffff0000u);
    int pend = of1;
    int bgcur = bg0;
    float acc = 0.f;
    const int base = of0;
    const int pstop = of8;
    const int nedges = pstop - base;
    const int ngroups = (nedges + 7) >> 3;

#define ADVANCE()                                                              \
    {                                                                          \
        float hv = fmaxf(acc + skcur, 0.f);                                    \
        atomicAdd(&P.psum[(size_t)bgcur * H + lane], hv);                      \
        ++idx;                                                                 \
        unsigned kv = sel8u(kp0, kp1, kp2, kp3, kp4, kp5, kp6, kp7, idx);      \
        kcur = __uint_as_float(kv << 16);                                      \
        skcur = __uint_as_float(kv & 0xffff0000u);                             \
        pend = sel8i(of1, of2, of3, of4, of5, of6, of7, of8, idx);             \
        bgcur = sel8i(bg0, bg1, bg2, bg3, bg4, bg5, bg6, bg7, idx);            \
        acc = 0.f;                                                             \
    }

#define ISSUE(RING, M, L8, GI)                                                 \
    if ((GI) < ngroups) {                                                      \
        _Pragma("unroll")                                                      \
        for (int j = 0; j < 8; ++j) {                                          \
            int s_ = __builtin_amdgcn_readlane((M).x, (L8) + j);               \
            RING[j] = qvp[(size_t)(unsigned)s_ * H + lane];                    \
        }                                                                      \
    }

#define CONSUME(RING, L8, GI)                                                  \
    if ((GI) < ngroups) {                                                      \
        const int e0 = (GI) * 8;                                               \
        int n_ = nedges - e0; if (n_ > 8) n_ = 8;                              \
        _Pragma("unroll")                                                      \
        for (int j = 0; j < 8; ++j) {                                          \
            if (j < n_) {                                                      \
                while (base + e0 + j >= pend) ADVANCE();                       \
                float e = fmaf(__int_as_float(                                 \
                    __builtin_amdgcn_readlane(Mc.y, (L8) + j)), weh, beh);     \
                float qq = __uint_as_float(RING[j] << 16);                     \
                float vv = __uint_as_float(RING[j] & 0xffff0000u);             \
                float g2 = fmaf(TWO_L2E, e, kcur + qq);                        \
                float sg = __builtin_amdgcn_rcpf(1.0f + __builtin_amdgcn_exp2f(-g2)); \
                acc = fmaf(sg, vv + e, acc);                                   \
            }                                                                  \
        }                                                                      \
    }

    if (nedges > 0) {
        int pos0 = base + lane; if (pos0 > pstop - 1) pos0 = pstop - 1;
        int2 Mc = meta[pos0];
        int2 Mn = Mc;
        if (nedges > 64) {
            int pos1 = base + 64 + lane; if (pos1 > pstop - 1) pos1 = pstop - 1;
            Mn = meta[pos1];
        }
        unsigned r0[8], r1[8], r2[8], r3[8];
        ISSUE(r0, Mc, 0, 0);
        ISSUE(r1, Mc, 8, 1);
        const int nsb = (ngroups + 7) >> 3;
        int sbg = 0;
        for (int sbi = 0; sbi < nsb; ++sbi, sbg += 8) {
            ISSUE(r2, Mc, 16, sbg + 2); CONSUME(r0, 0,  sbg + 0);
            ISSUE(r3, Mc, 24, sbg + 3); CONSUME(r1, 8,  sbg + 1);
            ISSUE(r0, Mc, 32, sbg + 4); CONSUME(r2, 16, sbg + 2);
            ISSUE(r1, Mc, 40, sbg + 5); CONSUME(r3, 24, sbg + 3);
            ISSUE(r2, Mc, 48, sbg + 6); CONSUME(r0, 32, sbg + 4);
            ISSUE(r3, Mc, 56, sbg + 7); CONSUME(r1, 40, sbg + 5);
            ISSUE(r0, Mn, 0,  sbg + 8); CONSUME(r2, 48, sbg + 6);
            ISSUE(r1, Mn, 8,  sbg + 9); CONSUME(r3, 56, sbg + 7);
            Mc = Mn;
            if ((sbi + 2) * 64 < nedges) {
                int pos = base + (sbi + 2) * 64 + lane;
                if (pos > pstop - 1) pos = pstop - 1;
                Mn = meta[pos];
            }
        }
    }
#undef ISSUE
#undef CONSUME

    for (;;) {
        float hv = fmaxf(acc + skcur, 0.f);
        atomicAdd(&P.psum[(size_t)bgcur * H + lane], hv);
        ++idx;
        if (idx >= ndst) break;
        unsigned kv = sel8u(kp0, kp1, kp2, kp3, kp4, kp5, kp6, kp7, idx);
        kcur = __uint_as_float(kv << 16);
        skcur = __uint_as_float(kv & 0xffff0000u);
        bgcur = sel8i(bg0, bg1, bg2, bg3, bg4, bg5, bg6, bg7, idx);
        acc = 0.f;
    }
#undef ADVANCE
}

// ---------------- MLP with fused per-graph counts ----------------
__global__ __launch_bounds__(64) void mlp_kernel(
    const float* __restrict__ sum_c, const float* __restrict__ sum_b,
    const int* __restrict__ batch_c, int Nc,
    const int* __restrict__ batch_b, int Nb,
    const float* __restrict__ W1, const float* __restrict__ b1,
    const float* __restrict__ W2, const float* __restrict__ b2,
    const float* __restrict__ W3, const float* __restrict__ b3,
    const float* __restrict__ Wout, const float* __restrict__ bout,
    float* __restrict__ out)
{
    const int g = blockIdx.x;
    const int h = threadIdx.x;
    __shared__ float pld[2 * H];
    __shared__ float hbuf[H];
    __shared__ float cnts[2];
    if (h < 2) {
        const int* a = h ? batch_b : batch_c;
        const int n = h ? Nb : Nc;
        int lo = lower_bound_i(a, n, g);
        int hi = lower_bound_i(a, n, g + 1);
        cnts[h] = fmaxf((float)(hi - lo), 1.f);
    }
    __syncthreads();
    pld[h] = sum_c[g * H + h] / cnts[0];
    pld[H + h] = sum_b[g * H + h] / cnts[1];
    __syncthreads();
    float a1 = b1[h];
    for (int j = 0; j < 2 * H; ++j) a1 = fmaf(pld[j], W1[j * H + h], a1);
    a1 = fmaxf(a1, 0.f);
    __syncthreads();
    hbuf[h] = a1;
    __syncthreads();
    float a2 = b2[h];
    for (int j = 0; j < H; ++j) a2 = fmaf(hbuf[j], W2[j * H + h], a2);
    a2 = fmaxf(a2, 0.f);
    __syncthreads();
    hbuf[h] = a2;
    __syncthreads();
    float a3 = b3[h];
    for (int j = 0; j < H; ++j) a3 = fmaf(hbuf[j], W3[j * H + h], a3);
    a3 = fmaxf(a3, 0.f);
    float p = a3 * Wout[h];
#pragma unroll
    for (int off = 32; off > 0; off >>= 1) p += __shfl_down(p, off, 64);
    if (h == 0) out[g] = p + bout[0];
}

extern "C" void kernel_launch(void* const* d_in, const int* in_sizes, int n_in,
                              void* d_out, int out_size, void* d_ws, size_t ws_size,
                              hipStream_t stream) {
    const float* x_x   = (const float*)d_in[0];
    const float* x_c   = (const float*)d_in[1];
    const float* x_b   = (const float*)d_in[2];
    const float* ea_ac = (const float*)d_in[3];
    const float* ea_cb = (const float*)d_in[4];

    const float* Wk_ac = (const float*)d_in[5];
    const float* Wq_ac = (const float*)d_in[6];
    const float* Wv_ac = (const float*)d_in[7];
    const float* Wskip_ac = (const float*)d_in[8];
    const float* We_ac = (const float*)d_in[9];
    const float* bk_ac = (const float*)d_in[10];
    const float* bq_ac = (const float*)d_in[11];
    const float* bv_ac = (const float*)d_in[12];
    const float* be_ac = (const float*)d_in[13];
    const float* bconv_ac = (const float*)d_in[14];

    const float* Wk_cb = (const float*)d_in[15];
    const float* Wq_cb = (const float*)d_in[16];
    const float* Wv_cb = (const float*)d_in[17];
    const float* Wskip_cb = (const float*)d_in[18];
    const float* We_cb = (const float*)d_in[19];
    const float* bk_cb = (const float*)d_in[20];
    const float* bq_cb = (const float*)d_in[21];
    const float* bv_cb = (const float*)d_in[22];
    const float* be_cb = (const float*)d_in[23];
    const float* bconv_cb = (const float*)d_in[24];

    const float* W1 = (const float*)d_in[25];
    const float* b1 = (const float*)d_in[26];
    const float* W2 = (const float*)d_in[27];
    const float* b2 = (const float*)d_in[28];
    const float* W3 = (const float*)d_in[29];
    const float* b3 = (const float*)d_in[30];
    const float* Wout = (const float*)d_in[31];
    const float* bout = (const float*)d_in[32];

    const int* src_ac = (const int*)d_in[33];
    const int* dst_ac = (const int*)d_in[34];
    const int* src_cb = (const int*)d_in[35];
    const int* dst_cb = (const int*)d_in[36];
    const int* batch_c = (const int*)d_in[37];
    const int* batch_b = (const int*)d_in[38];

    const int Nx = in_sizes[0] / F;
    const int Nc = in_sizes[1] / F;
    const int Nb = in_sizes[2] / F;
    const int E1 = in_sizes[33];
    const int E2 = in_sizes[35];
    (void)n_in; (void)out_size;

    const int NT = Nc + Nb;
    const size_t ET = (size_t)E1 + E2;
    const int NMAX = (Nc > Nb ? Nc : Nb);
    const int EMAX = (E1 > E2 ? E1 : E2);
    const int SRCMAX = (Nx > Nc ? Nx : Nc);
    const size_t SUMS = 2 * NUM_G * H;

    const size_t wordsA = 2 * ET + (size_t)(NT + 1) + NT + 256 + SUMS
                        + (size_t)(Nx + Nc) * H + (size_t)(Nc + Nb) * H;
    const bool pathA = (ws_size >= wordsA * 4);

    int* ws = (int*)d_ws;
    const size_t metaN = pathA ? 2 * ET : 2 * (size_t)EMAX;
    const int nOff = pathA ? NT : NMAX;
    int2*     meta    = (int2*)ws;
    int*      offsets = ws + metaN;
    int*      cnt     = offsets + (nOff + 1);
    int*      bsums   = cnt + nOff;
    float*    sum_c   = (float*)(bsums + 256);
    float*    sum_b   = sum_c + NUM_G * H;
    unsigned* qvp     = (unsigned*)(sum_b + NUM_G * H);
    unsigned* kskp    = qvp + (size_t)(pathA ? (Nx + Nc) : SRCMAX) * H;

    const int nC0 = (Nc + DPW - 1) / DPW;
    const int nC1 = (Nb + DPW - 1) / DPW;

    RelP P0, P1;
    P0.We = We_ac; P0.be = be_ac; P0.batch = batch_c; P0.psum = sum_c;
    P0.Ndst = Nc; P0.offBase = 0; P0.kskBase = 0;
    P1.We = We_cb; P1.be = be_cb; P1.batch = batch_b; P1.psum = sum_b;
    P1.Ndst = Nb; P1.offBase = pathA ? Nc : 0; P1.kskBase = pathA ? Nc : 0;

    const int SCAT_BLOCKS = 8 * 256;

    if (pathA) {
        hipMemsetAsync(cnt, 0, (size_t)(NT + 256 + SUMS) * sizeof(int), stream);

        const int nScan = (NT + 2047) / 2048;
        const int EB = (int)((ET + 255) / 256);
        const int w1 = (Nx + PROJ_ROWS - 1) / PROJ_ROWS;
        const int w2 = w1 + (Nc + PROJ_ROWS - 1) / PROJ_ROWS;
        const int w3 = w2 + (Nc + PROJ_ROWS - 1) / PROJ_ROWS;
        const int wTot = w3 + (Nb + PROJ_ROWS - 1) / PROJ_ROWS;
        ProjSec s0 = { x_x, Wq_ac, bq_ac, Wv_ac, bv_ac, qvp, Nx, 0, L2E };
        ProjSec s1 = { x_c, Wq_cb, bq_cb, Wv_cb, bv_cb, qvp + (size_t)Nx * H, Nc, w1, L2E };
        ProjSec s2 = { x_c, Wk_ac, bk_ac, Wskip_ac, bconv_ac, kskp, Nc, w2, L2E };
        ProjSec s3 = { x_b, Wk_cb, bk_cb, Wskip_cb, bconv_cb, kskp + (size_t)Nc * H, Nb, w3, L2E };
        const int projB = (wTot + 3) / 4;

        hist_proj_kernel<<<EB + projB, 256, 0, stream>>>(
            dst_ac, E1, dst_cb, E2, Nc, cnt, EB, s0, s1, s2, s3, wTot);
        scan_partial<<<nScan, 256, 0, stream>>>(cnt, bsums, NT);
        scan_bsums<<<1, 256, 0, stream>>>(bsums, nScan);
        scan_final<<<nScan, 256, 0, stream>>>(cnt, bsums, offsets, NT);
        scatter_part_kernel<<<SCAT_BLOCKS, 256, 0, stream>>>(
            src_ac, dst_ac, ea_ac, E1, src_cb, dst_cb, ea_cb, E2,
            Nc, Nx, NT, cnt, meta);

        const int nW = nC0 + nC1;
        aggregate_v4<<<(nW + 3) / 4, 256, 0, stream>>>(
            P0, P1, qvp, kskp, offsets, meta, nC0, nW);
    } else {
        hipMemsetAsync(sum_c, 0, SUMS * sizeof(float), stream);
        for (int rel = 0; rel < 2; ++rel) {
            const int n = rel ? Nb : Nc;
            const int E = rel ? E2 : E1;
            const int Ns = rel ? Nc : Nx;
            const int* srcA = rel ? src_cb : src_ac;
            const int* dstA = rel ? dst_cb : dst_ac;
            const float* eaA = rel ? ea_cb : ea_ac;
            const float* xs = rel ? x_c : x_x;
            const float* xd = rel ? x_b : x_c;
            const float* Wq = rel ? Wq_cb : Wq_ac; const float* bq = rel ? bq_cb : bq_ac;
            const float* Wv = rel ? Wv_cb : Wv_ac; const float* bv = rel ? bv_cb : bv_ac;
            const float* Wk = rel ? Wk_cb : Wk_ac; const float* bk = rel ? bk_cb : bk_ac;
            const float* Wsk = rel ? Wskip_cb : Wskip_ac;
            const float* bcv = rel ? bconv_cb : bconv_ac;
            const int nScan = (n + 2047) / 2048;
            hipMemsetAsync(cnt, 0, n * sizeof(int), stream);
            const int w1 = (Ns + PROJ_ROWS - 1) / PROJ_ROWS;
            const int wTot = w1 + (n + PROJ_ROWS - 1) / PROJ_ROWS;
            ProjSec s0 = { xs, Wq, bq, Wv, bv, qvp, Ns, 0, L2E };
            ProjSec s1 = { xs, Wq, bq, Wv, bv, qvp, 0, w1, L2E };
            ProjSec s2 = { xd, Wk, bk, Wsk, bcv, kskp, n, w1, L2E };
            ProjSec s3 = { xd, Wk, bk, Wsk, bcv, kskp, 0, wTot, L2E };
            const int EB = (E + 255) / 256;
            const int projB = (wTot + 3) / 4;
            hist_proj_kernel<<<EB + projB, 256, 0, stream>>>(
                dstA, E, dstA, 0, 0, cnt, EB, s0, s1, s2, s3, wTot);
            scan_partial<<<nScan, 256, 0, stream>>>(cnt, bsums, n);
            scan_bsums<<<1, 256, 0, stream>>>(bsums, nScan);
            scan_final<<<nScan, 256, 0, stream>>>(cnt, bsums, offsets, n);
            scatter_part_kernel<<<SCAT_BLOCKS, 256, 0, stream>>>(
                srcA, dstA, eaA, E, srcA, dstA, eaA, 0, 0, 0, n, cnt, meta);
            RelP PR = rel ? P1 : P0;
            const int nCr = rel ? nC1 : nC0;
            aggregate_v4<<<(nCr + 3) / 4, 256, 0, stream>>>(
                PR, PR, qvp, kskp, offsets, meta, nCr, nCr);
        }
    }

    mlp_kernel<<<NUM_G, 64, 0, stream>>>(
        sum_c, sum_b, batch_c, Nc, batch_b, Nb,
        W1, b1, W2, b2, W3, b3, Wout, bout, (float*)d_out);
}